// Round 2
// baseline (1102.652 us; speedup 1.0000x reference)
//
#include <hip/hip_runtime.h>

typedef unsigned long long u64;
typedef unsigned int u32;

#define FEAT 52
#define NPIX 2704          // 52*52
#define NANC 24336         // NPIX*9
#define PRE  12000
#define POST 2000
#define NSORT 32768
#define ROWW 192           // u64 words per mask row (12288 bits = 24 chunks * 512)

// ---- d_out layout (float elements) ----
#define ROIS_OFF 0
#define LOCS_OFF 8000
#define CLS_OFF  105344
#define OBJ_OFF  154016
#define CLS2_OFF 178352

// ---- ws layout (byte offsets) ----
#define OFF_X64   0ull          //  692224 f64
#define OFF_H64   5537792ull    //  692224 f64
#define OFF_REG64 11075584ull   //   97344 f64
#define OFF_SC64  11854336ull   //   24336 f64
#define OFF_ROI64 12049024ull   //   97344 f64
#define OFF_KEYS  12827776ull   //   32768 u64
#define OFF_SBOX  13089920ull   //   49152 f64
#define OFF_SAREA 13483136ull   //   12288 f64
#define OFF_SUPP  13581440ull   //     192 u64
#define OFF_MASK  13582976ull   //   12000*192 u64 = 18432000 B  (end ~32.0 MB)

// ---------------------------------------------------------------- prep: x -> f64
__global__ __launch_bounds__(256) void k_prep(const float* __restrict__ x,
                                              double* __restrict__ x64) {
    int t = blockIdx.x * 256 + threadIdx.x;   // grid 2704 -> exactly 692224
    x64[t] = (double)x[t];
}

// ---------------------------------------------------------------- conv 3x3 256->256 (f64)
__global__ __launch_bounds__(256) void k_conv3(const double* __restrict__ x64,
                                               const float* __restrict__ w,
                                               const float* __restrict__ b,
                                               double* __restrict__ h64) {
    __shared__ double wsh[9216];              // 4 oc * 256 ci * 9 taps = 72 KiB
    const int o0 = blockIdx.y * 4;
    for (int t = threadIdx.x; t < 9216; t += 256)
        wsh[t] = (double)w[o0 * 2304 + t];    // layout [oo][ci][k]
    __syncthreads();
    int p = blockIdx.x * 256 + threadIdx.x;
    if (p >= NPIX) return;
    int y = p / FEAT, xq = p % FEAT;
    double a0 = (double)b[o0+0], a1 = (double)b[o0+1];
    double a2 = (double)b[o0+2], a3 = (double)b[o0+3];
    int offs[9]; bool vm[9];
    #pragma unroll
    for (int kh = 0; kh < 3; ++kh) {
        #pragma unroll
        for (int kw = 0; kw < 3; ++kw) {
            int iy = y + kh - 1, ix = xq + kw - 1;
            bool v = ((unsigned)iy < (unsigned)FEAT) && ((unsigned)ix < (unsigned)FEAT);
            vm[kh*3+kw] = v;
            offs[kh*3+kw] = v ? iy*FEAT + ix : 0;
        }
    }
    for (int ci = 0; ci < 256; ++ci) {
        const double* xb = x64 + ci * NPIX;
        double xv[9];
        #pragma unroll
        for (int k = 0; k < 9; ++k) { double t = xb[offs[k]]; xv[k] = vm[k] ? t : 0.0; }
        const double* wr = wsh + ci * 9;
        #pragma unroll
        for (int k = 0; k < 9; ++k) {
            a0 += xv[k] * wr[k];
            a1 += xv[k] * wr[k + 2304];
            a2 += xv[k] * wr[k + 4608];
            a3 += xv[k] * wr[k + 6912];
        }
    }
    h64[(o0+0)*NPIX + p] = a0;
    h64[(o0+1)*NPIX + p] = a1;
    h64[(o0+2)*NPIX + p] = a2;
    h64[(o0+3)*NPIX + p] = a3;
}

// ---------------------------------------------------------------- 1x1 convs (reg 36 + cls 18)
__global__ __launch_bounds__(256) void k_conv1(const double* __restrict__ h64,
                                               const float* __restrict__ regw,
                                               const float* __restrict__ regb,
                                               const float* __restrict__ clsw,
                                               const float* __restrict__ clsb,
                                               float* __restrict__ out,
                                               double* __restrict__ reg64,
                                               double* __restrict__ score64) {
    int oc = blockIdx.y;                       // 0..53
    int p  = blockIdx.x * 256 + threadIdx.x;
    if (p >= NPIX) return;
    const float* wr; double bias;
    if (oc < 36) { wr = regw + oc * 256;      bias = (double)regb[oc]; }
    else         { wr = clsw + (oc-36) * 256; bias = (double)clsb[oc-36]; }
    double acc = bias;
    #pragma unroll 8
    for (int ci = 0; ci < 256; ++ci)
        acc += h64[ci * NPIX + p] * (double)wr[ci];
    float v = (float)acc;
    if (oc < 36) {
        out[LOCS_OFF + p*36 + oc] = v;
        reg64[p*36 + oc] = acc;                // == reg64[4*t + j], t = p*9+a
    } else {
        int c = oc - 36;
        out[CLS_OFF  + p*18 + c] = v;
        out[CLS2_OFF + p*18 + c] = v;
        if (c & 1) {
            out[OBJ_OFF + p*9 + (c >> 1)] = v;
            score64[p*9 + (c >> 1)] = acc;
        }
    }
}

// ---------------------------------------------------------------- decode + sort keys
__global__ __launch_bounds__(256) void k_decode(const double* __restrict__ reg64,
                                                const double* __restrict__ score64,
                                                double* __restrict__ roi64,
                                                u64* __restrict__ keys) {
    int t = blockIdx.x * 256 + threadIdx.x;    // grid 128 -> 32768
    if (t >= NANC) { keys[t] = ~0ull; return; }
    int pos = t / 9, a = t % 9;
    int py = pos / FEAT, px = pos % FEAT;
    int ri = a / 3, si = a % 3;
    double rat = (ri == 0) ? 0.5 : (ri == 1 ? 1.0 : 2.0);
    double scl = (si == 0) ? 4.0 : (si == 1 ? 8.0 : 16.0);
    double hA = 4.0 * scl * sqrt(rat);
    double wA = 4.0 * scl * sqrt(1.0 / rat);
    double cy0 = 4.0 * py + 2.0, cx0 = 4.0 * px + 2.0;
    // anchors go through f32 exactly like make_anchors().astype(float32)
    float y1f = (float)(cy0 - hA / 2.0), x1f = (float)(cx0 - wA / 2.0);
    float y2f = (float)(cy0 + hA / 2.0), x2f = (float)(cx0 + wA / 2.0);
    double ah = (double)y2f - (double)y1f, aw = (double)x2f - (double)x1f;
    double acy = (double)y1f + 0.5 * ah, acx = (double)x1f + 0.5 * aw;
    double l0 = reg64[4*t+0], l1 = reg64[4*t+1], l2 = reg64[4*t+2], l3 = reg64[4*t+3];
    double cy = l0 * ah + acy, cx = l1 * aw + acx;
    double hh = exp(l2) * ah,  ww = exp(l3) * aw;
    double r0 = fmin(fmax(cy - 0.5*hh, 0.0), 210.0);
    double r1 = fmin(fmax(cx - 0.5*ww, 0.0), 210.0);
    double r2 = fmin(fmax(cy + 0.5*hh, 0.0), 210.0);
    double r3 = fmin(fmax(cx + 0.5*ww, 0.0), 210.0);
    roi64[4*t+0] = r0; roi64[4*t+1] = r1; roi64[4*t+2] = r2; roi64[4*t+3] = r3;
    bool valid = (r2 - r0 >= 16.0) && (r3 - r1 >= 16.0);
    double m = valid ? score64[t] : -__builtin_huge_val();
    long long ll = __double_as_longlong(m);
    u64 u = (u64)ll;
    u64 mono = (ll < 0) ? ~u : (u ^ 0x8000000000000000ull); // ascending numeric
    keys[t] = ((~mono) & 0xFFFFFFFFFFFF0000ull) | (u64)t;   // asc key = desc score, stable
}

// ---------------------------------------------------------------- bitonic sort pieces
__global__ __launch_bounds__(1024) void k_sortA(u64* __restrict__ keys) {
    __shared__ u64 s[8192];                    // 64 KiB
    const int base = blockIdx.x * 8192;
    for (int t = threadIdx.x; t < 8192; t += 1024) s[t] = keys[base + t];
    __syncthreads();
    for (int k = 2; k <= 8192; k <<= 1) {
        for (int j = k >> 1; j > 0; j >>= 1) {
            for (int q = threadIdx.x; q < 4096; q += 1024) {
                int i = ((q & ~(j-1)) << 1) | (q & (j-1));
                int l = i | j;
                bool asc = (((base + i) & k) == 0);
                u64 A = s[i], B = s[l];
                bool sw = asc ? (A > B) : (A < B);
                if (sw) { s[i] = B; s[l] = A; }
            }
            __syncthreads();
        }
    }
    for (int t = threadIdx.x; t < 8192; t += 1024) keys[base + t] = s[t];
}

__global__ __launch_bounds__(1024) void k_sortB(u64* __restrict__ keys, int k) {
    __shared__ u64 s[8192];
    const int base = blockIdx.x * 8192;
    for (int t = threadIdx.x; t < 8192; t += 1024) s[t] = keys[base + t];
    __syncthreads();
    for (int j = 4096; j > 0; j >>= 1) {
        for (int q = threadIdx.x; q < 4096; q += 1024) {
            int i = ((q & ~(j-1)) << 1) | (q & (j-1));
            int l = i | j;
            bool asc = (((base + i) & k) == 0);
            u64 A = s[i], B = s[l];
            bool sw = asc ? (A > B) : (A < B);
            if (sw) { s[i] = B; s[l] = A; }
        }
        __syncthreads();
    }
    for (int t = threadIdx.x; t < 8192; t += 1024) keys[base + t] = s[t];
}

__global__ __launch_bounds__(256) void k_sortG(u64* __restrict__ keys, int k, int j) {
    int t = blockIdx.x * 256 + threadIdx.x;    // 16384 pairs
    int i = ((t & ~(j-1)) << 1) | (t & (j-1));
    int l = i | j;
    bool asc = ((i & k) == 0);
    u64 A = keys[i], B = keys[l];
    bool sw = asc ? (A > B) : (A < B);
    if (sw) { keys[i] = B; keys[l] = A; }
}

// ---------------------------------------------------------------- gather top-12000
__global__ __launch_bounds__(256) void k_gather(const u64* __restrict__ keys,
                                                const double* __restrict__ roi64,
                                                double* __restrict__ sbox,
                                                double* __restrict__ sarea,
                                                u64* __restrict__ suppinit) {
    int p = blockIdx.x * 256 + threadIdx.x;    // grid 48 -> 12288
    bool sup = true;
    if (p < PRE) {
        int idx = (int)(keys[p] & 0xFFFFull);
        double b0 = roi64[4*idx+0], b1 = roi64[4*idx+1];
        double b2 = roi64[4*idx+2], b3 = roi64[4*idx+3];
        sbox[4*p+0] = b0; sbox[4*p+1] = b1; sbox[4*p+2] = b2; sbox[4*p+3] = b3;
        sarea[p] = (b3 - b1 + 1.0) * (b2 - b0 + 1.0);
        sup = !((b2 - b0 >= 16.0) && (b3 - b1 >= 16.0));
    } else {
        sbox[4*p+0] = 0.0; sbox[4*p+1] = 0.0; sbox[4*p+2] = 0.0; sbox[4*p+3] = 0.0;
        sarea[p] = 1.0;
    }
    u64 ball = __ballot(sup);
    if ((threadIdx.x & 63) == 0) suppinit[p >> 6] = ball;
}

// ---------------------------------------------------------------- suppression bit matrix
__global__ __launch_bounds__(256) void k_mask(const double* __restrict__ sbox,
                                              const double* __restrict__ sarea,
                                              u64* __restrict__ mask) {
    const int jt = blockIdx.x, it = blockIdx.y;     // (12, 188)
    const int ib = it * 64, jb0 = jt * 1024;
    if (jb0 + 1023 <= ib) {                         // whole tile has j <= i -> zeros
        for (int t = threadIdx.x; t < 1024; t += 256) {
            int ti = t >> 4, w = t & 15;
            int i = ib + ti;
            if (i < PRE) mask[(size_t)i * ROWW + jt*16 + w] = 0ull;
        }
        return;
    }
    __shared__ double jbx[4096];
    __shared__ double jar[1024];
    for (int t = threadIdx.x; t < 4096; t += 256) jbx[t] = sbox[(size_t)jb0*4 + t];
    for (int t = threadIdx.x; t < 1024; t += 256) jar[t] = sarea[jb0 + t];
    __syncthreads();
    int ti = threadIdx.x >> 2;
    int i = ib + ti;
    if (i >= PRE) return;
    double iy1 = sbox[4*i+0], ix1 = sbox[4*i+1], iy2 = sbox[4*i+2], ix2 = sbox[4*i+3];
    double iar = sarea[i];
    for (int w = (threadIdx.x & 3); w < 16; w += 4) {
        u64 bits = 0ull;
        int q0 = w * 64;
        for (int l = 0; l < 64; ++l) {
            int q = q0 + l;
            double jy1 = jbx[4*q+0], jx1 = jbx[4*q+1], jy2 = jbx[4*q+2], jx2 = jbx[4*q+3];
            double yy1 = fmax(iy1, jy1), xx1 = fmax(ix1, jx1);
            double yy2 = fmin(iy2, jy2), xx2 = fmin(ix2, jx2);
            double iw = fmax(xx2 - xx1 + 1.0, 0.0);
            double ih = fmax(yy2 - yy1 + 1.0, 0.0);
            double inter = iw * ih;
            bool s = ((jb0 + q) > i) && (inter > 0.7 * (iar + jar[q] - inter));
            bits |= ((u64)s) << l;
        }
        mask[(size_t)i * ROWW + jt*16 + w] = bits;
    }
}

// ---------------------------------------------------------------- helpers for k_scan
__device__ inline u32 rdl32(u32 v, int l) {
    return (u32)__builtin_amdgcn_readlane((int)v, l);
}
__device__ inline u64 rdl64(u64 v, int l) {
    u32 lo = rdl32((u32)v, l);
    u32 hi = rdl32((u32)(v >> 32), l);
    return ((u64)hi << 32) | (u64)lo;
}
__device__ inline u64 sel8(u64 s0, u64 s1, u64 s2, u64 s3,
                           u64 s4, u64 s5, u64 s6, u64 s7, int w) {
    u64 r = s0;
    r = (w == 1) ? s1 : r;  r = (w == 2) ? s2 : r;
    r = (w == 3) ? s3 : r;  r = (w == 4) ? s4 : r;
    r = (w == 5) ? s5 : r;  r = (w == 6) ? s6 : r;
    r = (w == 7) ? s7 : r;
    return r;
}

// ---------------------------------------------------------------- NMS scan v2:
// wave0 = batch-parallel serial resolution (64 candidate rows loaded per LDS
// latency, resolution via ballot + readlane broadcast); waves 1..15 prefetch
// next chunk's diagonal block; supp words for the next chunk computed JIT
// from the global kept list (no cross-chunk full-width OR passes).
__global__ __launch_bounds__(1024) void k_scan(const u64* __restrict__ mask,
                                               const u64* __restrict__ suppinit,
                                               const double* __restrict__ sbox,
                                               float* __restrict__ rois) {
    __shared__ u64 dbuf[2][4096];     // [buf][row*8+w], 512 rows x 8 words, 64 KiB
    __shared__ u32 keptLDS[POST];     // global sorted indices of kept boxes
    __shared__ u32 supp8[2][16];      // next-chunk supp words as u32 pairs
    __shared__ int rankS, doneS;
    const int tid = threadIdx.x;
    const u32* suppinit32 = (const u32*)suppinit;

    // prologue: diag chunk 0, supp8[0], counters
    if (tid < 16) supp8[0][tid] = suppinit32[tid];
    if (tid == 0) { rankS = 0; doneS = 0; }
    for (int q = tid; q < 4096; q += 1024) {
        int r = q >> 3, w = q & 7;
        dbuf[0][q] = (r < PRE) ? mask[(size_t)r * ROWW + w] : 0ull;
    }
    __syncthreads();

    for (int c = 0; c < 24; ++c) {
        const int nc = c + 1;
        const int cb = c & 1, nb = nc & 1;
        if (tid < 64) {
            // ---------- wave 0: scan chunk c ----------
            const int lane = tid;
            if (lane < 16 && nc < 24) supp8[nb][lane] = suppinit32[nc*16 + lane];
            u64 st0 = (u64)supp8[cb][0]  | ((u64)supp8[cb][1]  << 32);
            u64 st1 = (u64)supp8[cb][2]  | ((u64)supp8[cb][3]  << 32);
            u64 st2 = (u64)supp8[cb][4]  | ((u64)supp8[cb][5]  << 32);
            u64 st3 = (u64)supp8[cb][6]  | ((u64)supp8[cb][7]  << 32);
            u64 st4 = (u64)supp8[cb][8]  | ((u64)supp8[cb][9]  << 32);
            u64 st5 = (u64)supp8[cb][10] | ((u64)supp8[cb][11] << 32);
            u64 st6 = (u64)supp8[cb][12] | ((u64)supp8[cb][13] << 32);
            u64 st7 = (u64)supp8[cb][14] | ((u64)supp8[cb][15] << 32);
            int frontier = 0;
            int rk = rankS;
            bool dn = false;
            while (true) {
                // zero bits >= frontier of st = candidates
                u64 z0,z1,z2,z3,z4,z5,z6,z7;
                {
                    #define ZW(W) { int rel = frontier - (W<<6); \
                        u64 fm = (rel <= 0) ? ~0ull : ((rel >= 64) ? 0ull : (~0ull << rel)); \
                        z##W = (~st##W) & fm; }
                    ZW(0) ZW(1) ZW(2) ZW(3) ZW(4) ZW(5) ZW(6) ZW(7)
                    #undef ZW
                }
                int tot = __builtin_popcountll(z0) + __builtin_popcountll(z1)
                        + __builtin_popcountll(z2) + __builtin_popcountll(z3)
                        + __builtin_popcountll(z4) + __builtin_popcountll(z5)
                        + __builtin_popcountll(z6) + __builtin_popcountll(z7);
                if (tot == 0) break;
                // lane picks its (lane)-th candidate
                int need = lane, myw = -1; u64 x = 0;
                #define PICK(W) { int cw = __builtin_popcountll(z##W); \
                    if (myw < 0) { if (need < cw) { myw = W; x = z##W; } else need -= cw; } }
                PICK(0) PICK(1) PICK(2) PICK(3) PICK(4) PICK(5) PICK(6) PICK(7)
                #undef PICK
                const bool have = (myw >= 0);
                int pos = 0;
                if (have) {
                    #pragma unroll
                    for (int sh = 32; sh >= 1; sh >>= 1) {
                        u64 lowm = (1ull << sh) - 1ull;
                        int cc = __builtin_popcountll(x & lowm);
                        if (need >= cc) { need -= cc; x >>= sh; pos += sh; }
                    }
                }
                const int cand = have ? ((myw << 6) | pos) : 0;
                // parallel row load from LDS diag
                u64 r0=0,r1=0,r2=0,r3=0,r4=0,r5=0,r6=0,r7=0;
                if (have) {
                    const u64* dr = &dbuf[cb][cand << 3];
                    r0=dr[0]; r1=dr[1]; r2=dr[2]; r3=dr[3];
                    r4=dr[4]; r5=dr[5]; r6=dr[6]; r7=dr[7];
                }
                // resolve candidates in ascending order
                u64 sw0 = sel8(st0,st1,st2,st3,st4,st5,st6,st7, myw);
                int tst = (int)((sw0 >> (cand & 63)) & 1ull);
                u64 alive = __ballot(have && !tst);
                while (alive) {
                    int l = __builtin_ctzll(alive);
                    st0 |= rdl64(r0, l); st1 |= rdl64(r1, l);
                    st2 |= rdl64(r2, l); st3 |= rdl64(r3, l);
                    st4 |= rdl64(r4, l); st5 |= rdl64(r5, l);
                    st6 |= rdl64(r6, l); st7 |= rdl64(r7, l);
                    int cbit = (int)rdl32((u32)cand, l);
                    if (lane == 0) keptLDS[rk] = (u32)(c*512 + cbit);
                    rk++;
                    if (rk >= POST) { dn = true; break; }
                    if (l >= 63) break;
                    u64 sw1 = sel8(st0,st1,st2,st3,st4,st5,st6,st7, myw);
                    int t2 = (int)((sw1 >> (cand & 63)) & 1ull);
                    alive = __ballot(have && !t2) & (~0ull << (l + 1));
                }
                if (dn) break;
                if (tot <= 64) break;                      // all remaining processed
                frontier = (int)rdl32((u32)cand, 63) + 1;  // lane 63's candidate
            }
            if (lane == 0) { rankS = rk; if (dn) doneS = 1; }
        } else if (nc < 24) {
            // ---------- waves 1..15: prefetch diag block of chunk nc ----------
            for (int q = tid - 64; q < 4096; q += 960) {
                int r = q >> 3, w = q & 7;
                int i = nc*512 + r;
                dbuf[nb][q] = (i < PRE) ? mask[(size_t)i * ROWW + nc*8 + w] : 0ull;
            }
        }
        __syncthreads();
        if (doneS || nc >= 24) break;
        // ---------- JIT supp words for chunk nc: OR over all kept rows ----------
        {
            int rk = rankS;
            int w = tid & 7;
            u64 acc = 0;
            for (int k = tid >> 3; k < rk; k += 128)
                acc |= mask[(size_t)keptLDS[k] * ROWW + nc*8 + w];
            if (acc) {
                atomicOr(&supp8[nb][2*w],     (u32)acc);
                atomicOr(&supp8[nb][2*w + 1], (u32)(acc >> 32));
            }
        }
        __syncthreads();
    }
    __syncthreads();
    const int R = rankS;
    for (int r = tid; r < POST; r += 1024) {
        if (r < R) {
            int p = (int)keptLDS[r];
            rois[4*r+0] = (float)sbox[4*p+0];
            rois[4*r+1] = (float)sbox[4*p+1];
            rois[4*r+2] = (float)sbox[4*p+2];
            rois[4*r+3] = (float)sbox[4*p+3];
        } // else stays zero (memset)
    }
}

// ---------------------------------------------------------------- launcher
extern "C" void kernel_launch(void* const* d_in, const int* in_sizes, int n_in,
                              void* d_out, int out_size, void* d_ws, size_t ws_size,
                              hipStream_t stream) {
    const float* x    = (const float*)d_in[0];
    const float* w1   = (const float*)d_in[1];
    const float* b1   = (const float*)d_in[2];
    const float* regw = (const float*)d_in[3];
    const float* regb = (const float*)d_in[4];
    const float* clsw = (const float*)d_in[5];
    const float* clsb = (const float*)d_in[6];
    float* out = (float*)d_out;

    char* ws = (char*)d_ws;
    double* x64    = (double*)(ws + OFF_X64);
    double* h64    = (double*)(ws + OFF_H64);
    double* reg64  = (double*)(ws + OFF_REG64);
    double* sc64   = (double*)(ws + OFF_SC64);
    double* roi64  = (double*)(ws + OFF_ROI64);
    u64*    keys   = (u64*)   (ws + OFF_KEYS);
    double* sbox   = (double*)(ws + OFF_SBOX);
    double* sarea  = (double*)(ws + OFF_SAREA);
    u64*    supp0  = (u64*)   (ws + OFF_SUPP);
    u64*    maskp  = (u64*)   (ws + OFF_MASK);

    hipMemsetAsync(d_out, 0, 8000 * sizeof(float), stream);  // rois zero-padding

    k_prep <<<2704, 256, 0, stream>>>(x, x64);
    k_conv3<<<dim3(11, 64), 256, 0, stream>>>(x64, w1, b1, h64);
    k_conv1<<<dim3(11, 54), 256, 0, stream>>>(h64, regw, regb, clsw, clsb, out, reg64, sc64);
    k_decode<<<128, 256, 0, stream>>>(reg64, sc64, roi64, keys);

    k_sortA<<<4, 1024, 0, stream>>>(keys);
    k_sortG<<<64, 256, 0, stream>>>(keys, 16384, 8192);
    k_sortB<<<4, 1024, 0, stream>>>(keys, 16384);
    k_sortG<<<64, 256, 0, stream>>>(keys, 32768, 16384);
    k_sortG<<<64, 256, 0, stream>>>(keys, 32768, 8192);
    k_sortB<<<4, 1024, 0, stream>>>(keys, 32768);

    k_gather<<<48, 256, 0, stream>>>(keys, roi64, sbox, sarea, supp0);
    k_mask<<<dim3(12, 188), 256, 0, stream>>>(sbox, sarea, maskp);
    k_scan<<<1, 1024, 0, stream>>>(maskp, supp0, sbox, out + ROIS_OFF);
}

// Round 3
// 799.327 us; speedup vs baseline: 1.3795x; 1.3795x over previous
//
#include <hip/hip_runtime.h>

typedef unsigned long long u64;
typedef unsigned int u32;

#define FEAT 52
#define NPIX 2704          // 52*52
#define NANC 24336         // NPIX*9
#define PRE  12000
#define POST 2000
#define NSORT 32768
#define ROWW 192           // u64 words per mask row (12288 bits = 24 chunks * 512)

// ---- d_out layout (float elements) ----
#define ROIS_OFF 0
#define LOCS_OFF 8000
#define CLS_OFF  105344
#define OBJ_OFF  154016
#define CLS2_OFF 178352

// ---- ws layout (byte offsets) ----
#define OFF_X64   0ull          //  692224 f64
#define OFF_H64   5537792ull    //  692224 f64
#define OFF_REG64 11075584ull   //   97344 f64
#define OFF_SC64  11854336ull   //   24336 f64
#define OFF_ROI64 12049024ull   //   97344 f64
#define OFF_KEYS  12827776ull   //   32768 u64
#define OFF_SBOX  13089920ull   //   49152 f64
#define OFF_SAREA 13483136ull   //   12288 f64
#define OFF_SUPP  13581440ull   //     192 u64
#define OFF_MASK  13582976ull   //   12000*192 u64 = 18432000 B  (end ~32.0 MB)

// ---------------------------------------------------------------- prep: x -> f64
__global__ __launch_bounds__(256) void k_prep(const float* __restrict__ x,
                                              double* __restrict__ x64) {
    int t = blockIdx.x * 256 + threadIdx.x;   // grid 2704 -> exactly 692224
    x64[t] = (double)x[t];
}

// ---------------------------------------------------------------- conv 3x3 256->256 (f64)
__global__ __launch_bounds__(256) void k_conv3(const double* __restrict__ x64,
                                               const float* __restrict__ w,
                                               const float* __restrict__ b,
                                               double* __restrict__ h64) {
    __shared__ double wsh[9216];              // 4 oc * 256 ci * 9 taps = 72 KiB
    const int o0 = blockIdx.y * 4;
    for (int t = threadIdx.x; t < 9216; t += 256)
        wsh[t] = (double)w[o0 * 2304 + t];    // layout [oo][ci][k]
    __syncthreads();
    int p = blockIdx.x * 256 + threadIdx.x;
    if (p >= NPIX) return;
    int y = p / FEAT, xq = p % FEAT;
    double a0 = (double)b[o0+0], a1 = (double)b[o0+1];
    double a2 = (double)b[o0+2], a3 = (double)b[o0+3];
    int offs[9]; bool vm[9];
    #pragma unroll
    for (int kh = 0; kh < 3; ++kh) {
        #pragma unroll
        for (int kw = 0; kw < 3; ++kw) {
            int iy = y + kh - 1, ix = xq + kw - 1;
            bool v = ((unsigned)iy < (unsigned)FEAT) && ((unsigned)ix < (unsigned)FEAT);
            vm[kh*3+kw] = v;
            offs[kh*3+kw] = v ? iy*FEAT + ix : 0;
        }
    }
    for (int ci = 0; ci < 256; ++ci) {
        const double* xb = x64 + ci * NPIX;
        double xv[9];
        #pragma unroll
        for (int k = 0; k < 9; ++k) { double t = xb[offs[k]]; xv[k] = vm[k] ? t : 0.0; }
        const double* wr = wsh + ci * 9;
        #pragma unroll
        for (int k = 0; k < 9; ++k) {
            a0 += xv[k] * wr[k];
            a1 += xv[k] * wr[k + 2304];
            a2 += xv[k] * wr[k + 4608];
            a3 += xv[k] * wr[k + 6912];
        }
    }
    h64[(o0+0)*NPIX + p] = a0;
    h64[(o0+1)*NPIX + p] = a1;
    h64[(o0+2)*NPIX + p] = a2;
    h64[(o0+3)*NPIX + p] = a3;
}

// ---------------------------------------------------------------- 1x1 convs (reg 36 + cls 18)
__global__ __launch_bounds__(256) void k_conv1(const double* __restrict__ h64,
                                               const float* __restrict__ regw,
                                               const float* __restrict__ regb,
                                               const float* __restrict__ clsw,
                                               const float* __restrict__ clsb,
                                               float* __restrict__ out,
                                               double* __restrict__ reg64,
                                               double* __restrict__ score64) {
    int oc = blockIdx.y;                       // 0..53
    int p  = blockIdx.x * 256 + threadIdx.x;
    if (p >= NPIX) return;
    const float* wr; double bias;
    if (oc < 36) { wr = regw + oc * 256;      bias = (double)regb[oc]; }
    else         { wr = clsw + (oc-36) * 256; bias = (double)clsb[oc-36]; }
    double acc = bias;
    #pragma unroll 8
    for (int ci = 0; ci < 256; ++ci)
        acc += h64[ci * NPIX + p] * (double)wr[ci];
    float v = (float)acc;
    if (oc < 36) {
        out[LOCS_OFF + p*36 + oc] = v;
        reg64[p*36 + oc] = acc;                // == reg64[4*t + j], t = p*9+a
    } else {
        int c = oc - 36;
        out[CLS_OFF  + p*18 + c] = v;
        out[CLS2_OFF + p*18 + c] = v;
        if (c & 1) {
            out[OBJ_OFF + p*9 + (c >> 1)] = v;
            score64[p*9 + (c >> 1)] = acc;
        }
    }
}

// ---------------------------------------------------------------- decode + sort keys
__global__ __launch_bounds__(256) void k_decode(const double* __restrict__ reg64,
                                                const double* __restrict__ score64,
                                                double* __restrict__ roi64,
                                                u64* __restrict__ keys) {
    int t = blockIdx.x * 256 + threadIdx.x;    // grid 128 -> 32768
    if (t >= NANC) { keys[t] = ~0ull; return; }
    int pos = t / 9, a = t % 9;
    int py = pos / FEAT, px = pos % FEAT;
    int ri = a / 3, si = a % 3;
    double rat = (ri == 0) ? 0.5 : (ri == 1 ? 1.0 : 2.0);
    double scl = (si == 0) ? 4.0 : (si == 1 ? 8.0 : 16.0);
    double hA = 4.0 * scl * sqrt(rat);
    double wA = 4.0 * scl * sqrt(1.0 / rat);
    double cy0 = 4.0 * py + 2.0, cx0 = 4.0 * px + 2.0;
    // anchors go through f32 exactly like make_anchors().astype(float32)
    float y1f = (float)(cy0 - hA / 2.0), x1f = (float)(cx0 - wA / 2.0);
    float y2f = (float)(cy0 + hA / 2.0), x2f = (float)(cx0 + wA / 2.0);
    double ah = (double)y2f - (double)y1f, aw = (double)x2f - (double)x1f;
    double acy = (double)y1f + 0.5 * ah, acx = (double)x1f + 0.5 * aw;
    double l0 = reg64[4*t+0], l1 = reg64[4*t+1], l2 = reg64[4*t+2], l3 = reg64[4*t+3];
    double cy = l0 * ah + acy, cx = l1 * aw + acx;
    double hh = exp(l2) * ah,  ww = exp(l3) * aw;
    double r0 = fmin(fmax(cy - 0.5*hh, 0.0), 210.0);
    double r1 = fmin(fmax(cx - 0.5*ww, 0.0), 210.0);
    double r2 = fmin(fmax(cy + 0.5*hh, 0.0), 210.0);
    double r3 = fmin(fmax(cx + 0.5*ww, 0.0), 210.0);
    roi64[4*t+0] = r0; roi64[4*t+1] = r1; roi64[4*t+2] = r2; roi64[4*t+3] = r3;
    bool valid = (r2 - r0 >= 16.0) && (r3 - r1 >= 16.0);
    double m = valid ? score64[t] : -__builtin_huge_val();
    long long ll = __double_as_longlong(m);
    u64 u = (u64)ll;
    u64 mono = (ll < 0) ? ~u : (u ^ 0x8000000000000000ull); // ascending numeric
    keys[t] = ((~mono) & 0xFFFFFFFFFFFF0000ull) | (u64)t;   // asc key = desc score, stable
}

// ---------------------------------------------------------------- bitonic sort pieces
__global__ __launch_bounds__(1024) void k_sortA(u64* __restrict__ keys) {
    __shared__ u64 s[8192];                    // 64 KiB
    const int base = blockIdx.x * 8192;
    for (int t = threadIdx.x; t < 8192; t += 1024) s[t] = keys[base + t];
    __syncthreads();
    for (int k = 2; k <= 8192; k <<= 1) {
        for (int j = k >> 1; j > 0; j >>= 1) {
            for (int q = threadIdx.x; q < 4096; q += 1024) {
                int i = ((q & ~(j-1)) << 1) | (q & (j-1));
                int l = i | j;
                bool asc = (((base + i) & k) == 0);
                u64 A = s[i], B = s[l];
                bool sw = asc ? (A > B) : (A < B);
                if (sw) { s[i] = B; s[l] = A; }
            }
            __syncthreads();
        }
    }
    for (int t = threadIdx.x; t < 8192; t += 1024) keys[base + t] = s[t];
}

__global__ __launch_bounds__(1024) void k_sortB(u64* __restrict__ keys, int k) {
    __shared__ u64 s[8192];
    const int base = blockIdx.x * 8192;
    for (int t = threadIdx.x; t < 8192; t += 1024) s[t] = keys[base + t];
    __syncthreads();
    for (int j = 4096; j > 0; j >>= 1) {
        for (int q = threadIdx.x; q < 4096; q += 1024) {
            int i = ((q & ~(j-1)) << 1) | (q & (j-1));
            int l = i | j;
            bool asc = (((base + i) & k) == 0);
            u64 A = s[i], B = s[l];
            bool sw = asc ? (A > B) : (A < B);
            if (sw) { s[i] = B; s[l] = A; }
        }
        __syncthreads();
    }
    for (int t = threadIdx.x; t < 8192; t += 1024) keys[base + t] = s[t];
}

__global__ __launch_bounds__(256) void k_sortG(u64* __restrict__ keys, int k, int j) {
    int t = blockIdx.x * 256 + threadIdx.x;    // 16384 pairs
    int i = ((t & ~(j-1)) << 1) | (t & (j-1));
    int l = i | j;
    bool asc = ((i & k) == 0);
    u64 A = keys[i], B = keys[l];
    bool sw = asc ? (A > B) : (A < B);
    if (sw) { keys[i] = B; keys[l] = A; }
}

// ---------------------------------------------------------------- gather top-12000
__global__ __launch_bounds__(256) void k_gather(const u64* __restrict__ keys,
                                                const double* __restrict__ roi64,
                                                double* __restrict__ sbox,
                                                double* __restrict__ sarea,
                                                u64* __restrict__ suppinit) {
    int p = blockIdx.x * 256 + threadIdx.x;    // grid 48 -> 12288
    bool sup = true;
    if (p < PRE) {
        int idx = (int)(keys[p] & 0xFFFFull);
        double b0 = roi64[4*idx+0], b1 = roi64[4*idx+1];
        double b2 = roi64[4*idx+2], b3 = roi64[4*idx+3];
        sbox[4*p+0] = b0; sbox[4*p+1] = b1; sbox[4*p+2] = b2; sbox[4*p+3] = b3;
        sarea[p] = (b3 - b1 + 1.0) * (b2 - b0 + 1.0);
        sup = !((b2 - b0 >= 16.0) && (b3 - b1 >= 16.0));
    } else {
        sbox[4*p+0] = 0.0; sbox[4*p+1] = 0.0; sbox[4*p+2] = 0.0; sbox[4*p+3] = 0.0;
        sarea[p] = 1.0;
    }
    u64 ball = __ballot(sup);
    if ((threadIdx.x & 63) == 0) suppinit[p >> 6] = ball;
}

// ---------------------------------------------------------------- suppression bit matrix
__global__ __launch_bounds__(256) void k_mask(const double* __restrict__ sbox,
                                              const double* __restrict__ sarea,
                                              u64* __restrict__ mask) {
    const int jt = blockIdx.x, it = blockIdx.y;     // (12, 188)
    const int ib = it * 64, jb0 = jt * 1024;
    if (jb0 + 1023 <= ib) {                         // whole tile has j <= i -> zeros
        for (int t = threadIdx.x; t < 1024; t += 256) {
            int ti = t >> 4, w = t & 15;
            int i = ib + ti;
            if (i < PRE) mask[(size_t)i * ROWW + jt*16 + w] = 0ull;
        }
        return;
    }
    __shared__ double jbx[4096];
    __shared__ double jar[1024];
    for (int t = threadIdx.x; t < 4096; t += 256) jbx[t] = sbox[(size_t)jb0*4 + t];
    for (int t = threadIdx.x; t < 1024; t += 256) jar[t] = sarea[jb0 + t];
    __syncthreads();
    int ti = threadIdx.x >> 2;
    int i = ib + ti;
    if (i >= PRE) return;
    double iy1 = sbox[4*i+0], ix1 = sbox[4*i+1], iy2 = sbox[4*i+2], ix2 = sbox[4*i+3];
    double iar = sarea[i];
    for (int w = (threadIdx.x & 3); w < 16; w += 4) {
        u64 bits = 0ull;
        int q0 = w * 64;
        for (int l = 0; l < 64; ++l) {
            int q = q0 + l;
            double jy1 = jbx[4*q+0], jx1 = jbx[4*q+1], jy2 = jbx[4*q+2], jx2 = jbx[4*q+3];
            double yy1 = fmax(iy1, jy1), xx1 = fmax(ix1, jx1);
            double yy2 = fmin(iy2, jy2), xx2 = fmin(ix2, jx2);
            double iw = fmax(xx2 - xx1 + 1.0, 0.0);
            double ih = fmax(yy2 - yy1 + 1.0, 0.0);
            double inter = iw * ih;
            bool s = ((jb0 + q) > i) && (inter > 0.7 * (iar + jar[q] - inter));
            bits |= ((u64)s) << l;
        }
        mask[(size_t)i * ROWW + jt*16 + w] = bits;
    }
}

// ---------------------------------------------------------------- helpers for k_scan
__device__ inline u64 rdl64(u64 v, int l) {
    u32 lo = (u32)__builtin_amdgcn_readlane((int)(u32)v, l);
    u32 hi = (u32)__builtin_amdgcn_readlane((int)(u32)(v >> 32), l);
    return ((u64)hi << 32) | (u64)lo;
}
#define RFL64(lo, hi) ( ((u64)(u32)__builtin_amdgcn_readfirstlane((int)(hi)) << 32) \
                      | (u64)(u32)__builtin_amdgcn_readfirstlane((int)(lo)) )

// ---------------------------------------------------------------- NMS scan v3:
// wave0 walks 64 consecutive bits per group; lane l preloads the 8-word row of
// bit l; serial chain per kept = s_ff1 + 2 readlane + s_andn2 (all other
// readlanes/acc-ORs off the critical chain, no ballots, no selects). Kept
// indices emitted once per group via mbcnt on the uniform kept-mask.
// Rows padded to 9 u64 (72B stride) to cap LDS bank conflicts at 4-way.
__global__ __launch_bounds__(1024) void k_scan(const u64* __restrict__ mask,
                                               const u64* __restrict__ suppinit,
                                               const double* __restrict__ sbox,
                                               float* __restrict__ rois) {
    __shared__ u64 dbuf[2][4608];     // [buf][row*9 + w], 512 rows x 8(+1 pad) words
    __shared__ u32 keptLDS[POST];     // global sorted indices of kept boxes
    __shared__ u32 supp8[2][16];      // chunk supp words as u32 pairs
    __shared__ int rankS, doneS;
    const int tid = threadIdx.x;
    const u32* suppinit32 = (const u32*)suppinit;

    if (tid < 16) supp8[0][tid] = suppinit32[tid];
    if (tid == 0) { rankS = 0; doneS = 0; }
    for (int q = tid; q < 4096; q += 1024) {
        int r = q >> 3, w = q & 7;
        dbuf[0][r*9 + w] = (r < PRE) ? mask[(size_t)r * ROWW + w] : 0ull;
    }
    __syncthreads();

    for (int c = 0; c < 24; ++c) {
        const int nc = c + 1;
        const int cb = c & 1, nb = nc & 1;
        if (tid < 64) {
            // ---------- wave 0: scan chunk c ----------
            const int lane = tid;
            if (lane < 16 && nc < 24) supp8[nb][lane] = suppinit32[nc*16 + lane];
            u64 i0 = RFL64(supp8[cb][0],  supp8[cb][1]);
            u64 i1 = RFL64(supp8[cb][2],  supp8[cb][3]);
            u64 i2 = RFL64(supp8[cb][4],  supp8[cb][5]);
            u64 i3 = RFL64(supp8[cb][6],  supp8[cb][7]);
            u64 i4 = RFL64(supp8[cb][8],  supp8[cb][9]);
            u64 i5 = RFL64(supp8[cb][10], supp8[cb][11]);
            u64 i6 = RFL64(supp8[cb][12], supp8[cb][13]);
            u64 i7 = RFL64(supp8[cb][14], supp8[cb][15]);
            u64 a0=0,a1=0,a2=0,a3=0,a4=0,a5=0,a6=0,a7=0;
            int rk = __builtin_amdgcn_readfirstlane(rankS);
            bool dn = false;
#define GROUP(G)                                                                \
            if (!dn) {                                                          \
                u64 z = ~(i##G | a##G);                                         \
                if (z) {                                                        \
                    const u64* rowp = &dbuf[cb][(G*64 + lane)*9];               \
                    u64 r0=rowp[0],r1=rowp[1],r2=rowp[2],r3=rowp[3];            \
                    u64 r4=rowp[4],r5=rowp[5],r6=rowp[6],r7=rowp[7];            \
                    u64 keptm = 0;                                              \
                    while (z) {                                                 \
                        int bpos = (int)__builtin_ctzll(z);                     \
                        u64 q0=rdl64(r0,bpos), q1=rdl64(r1,bpos);               \
                        u64 q2=rdl64(r2,bpos), q3=rdl64(r3,bpos);               \
                        u64 q4=rdl64(r4,bpos), q5=rdl64(r5,bpos);               \
                        u64 q6=rdl64(r6,bpos), q7=rdl64(r7,bpos);               \
                        keptm |= (1ull << bpos);                                \
                        z &= ~(1ull << bpos) & ~q##G;                           \
                        a0|=q0; a1|=q1; a2|=q2; a3|=q3;                         \
                        a4|=q4; a5|=q5; a6|=q6; a7|=q7;                         \
                    }                                                           \
                    int pc = __builtin_popcountll(keptm);                       \
                    int navail = POST - rk;                                     \
                    int mylot = __builtin_amdgcn_mbcnt_hi((u32)(keptm >> 32),   \
                                 __builtin_amdgcn_mbcnt_lo((u32)keptm, 0));     \
                    if (((keptm >> lane) & 1) && mylot < navail)                \
                        keptLDS[rk + mylot] = (u32)(c*512 + G*64 + lane);       \
                    if (pc >= navail) { rk = POST; dn = true; }                 \
                    else rk += pc;                                              \
                }                                                               \
            }
            GROUP(0) GROUP(1) GROUP(2) GROUP(3)
            GROUP(4) GROUP(5) GROUP(6) GROUP(7)
#undef GROUP
            if (lane == 0) { rankS = rk; if (dn) doneS = 1; }
        } else if (nc < 24) {
            // ---------- waves 1..15: prefetch diag block of chunk nc ----------
            for (int q = tid - 64; q < 4096; q += 960) {
                int r = q >> 3, w = q & 7;
                int i = nc*512 + r;
                dbuf[nb][r*9 + w] = (i < PRE) ? mask[(size_t)i * ROWW + nc*8 + w] : 0ull;
            }
        }
        __syncthreads();
        if (doneS || nc >= 24) break;
        // ---------- JIT supp words for chunk nc: OR over all kept rows ----------
        {
            int rk = rankS;
            int w = tid & 7;
            u64 acc = 0;
            for (int k = tid >> 3; k < rk; k += 128)
                acc |= mask[(size_t)keptLDS[k] * ROWW + nc*8 + w];
            if (acc) {
                atomicOr(&supp8[nb][2*w],     (u32)acc);
                atomicOr(&supp8[nb][2*w + 1], (u32)(acc >> 32));
            }
        }
        __syncthreads();
    }
    __syncthreads();
    const int R = rankS;
    for (int r = tid; r < POST; r += 1024) {
        if (r < R) {
            int p = (int)keptLDS[r];
            rois[4*r+0] = (float)sbox[4*p+0];
            rois[4*r+1] = (float)sbox[4*p+1];
            rois[4*r+2] = (float)sbox[4*p+2];
            rois[4*r+3] = (float)sbox[4*p+3];
        } // else stays zero (memset)
    }
}

// ---------------------------------------------------------------- launcher
extern "C" void kernel_launch(void* const* d_in, const int* in_sizes, int n_in,
                              void* d_out, int out_size, void* d_ws, size_t ws_size,
                              hipStream_t stream) {
    const float* x    = (const float*)d_in[0];
    const float* w1   = (const float*)d_in[1];
    const float* b1   = (const float*)d_in[2];
    const float* regw = (const float*)d_in[3];
    const float* regb = (const float*)d_in[4];
    const float* clsw = (const float*)d_in[5];
    const float* clsb = (const float*)d_in[6];
    float* out = (float*)d_out;

    char* ws = (char*)d_ws;
    double* x64    = (double*)(ws + OFF_X64);
    double* h64    = (double*)(ws + OFF_H64);
    double* reg64  = (double*)(ws + OFF_REG64);
    double* sc64   = (double*)(ws + OFF_SC64);
    double* roi64  = (double*)(ws + OFF_ROI64);
    u64*    keys   = (u64*)   (ws + OFF_KEYS);
    double* sbox   = (double*)(ws + OFF_SBOX);
    double* sarea  = (double*)(ws + OFF_SAREA);
    u64*    supp0  = (u64*)   (ws + OFF_SUPP);
    u64*    maskp  = (u64*)   (ws + OFF_MASK);

    hipMemsetAsync(d_out, 0, 8000 * sizeof(float), stream);  // rois zero-padding

    k_prep <<<2704, 256, 0, stream>>>(x, x64);
    k_conv3<<<dim3(11, 64), 256, 0, stream>>>(x64, w1, b1, h64);
    k_conv1<<<dim3(11, 54), 256, 0, stream>>>(h64, regw, regb, clsw, clsb, out, reg64, sc64);
    k_decode<<<128, 256, 0, stream>>>(reg64, sc64, roi64, keys);

    k_sortA<<<4, 1024, 0, stream>>>(keys);
    k_sortG<<<64, 256, 0, stream>>>(keys, 16384, 8192);
    k_sortB<<<4, 1024, 0, stream>>>(keys, 16384);
    k_sortG<<<64, 256, 0, stream>>>(keys, 32768, 16384);
    k_sortG<<<64, 256, 0, stream>>>(keys, 32768, 8192);
    k_sortB<<<4, 1024, 0, stream>>>(keys, 32768);

    k_gather<<<48, 256, 0, stream>>>(keys, roi64, sbox, sarea, supp0);
    k_mask<<<dim3(12, 188), 256, 0, stream>>>(sbox, sarea, maskp);
    k_scan<<<1, 1024, 0, stream>>>(maskp, supp0, sbox, out + ROIS_OFF);
}

// Round 5
// 768.275 us; speedup vs baseline: 1.4352x; 1.0404x over previous
//
#include <hip/hip_runtime.h>

typedef unsigned long long u64;
typedef unsigned int u32;

#define FEAT 52
#define NPIX 2704          // 52*52
#define NANC 24336         // NPIX*9
#define PRE  12000
#define POST 2000
#define NSORT 32768
#define ROWW 192           // u64 words per mask row (12288 bits = 24 chunks * 512)

// ---- d_out layout (float elements) ----
#define ROIS_OFF 0
#define LOCS_OFF 8000
#define CLS_OFF  105344
#define OBJ_OFF  154016
#define CLS2_OFF 178352

// ---- ws layout (byte offsets) ----
#define OFF_W64   0ull          //  589824 f64 (3x3 weights in f64)
#define OFF_H64   4718592ull    //  692224 f64
#define OFF_REG64 10256384ull   //   97344 f64
#define OFF_SC64  11035136ull   //   24336 f64
#define OFF_ROI64 11229824ull   //   97344 f64
#define OFF_KEYS  12008576ull   //   32768 u64
#define OFF_SBOX  12270720ull   //   49152 f64
#define OFF_SAREA 12663936ull   //   12288 f64
#define OFF_SUPP  12762240ull   //     192 u64
#define OFF_MASK  12763776ull   //   12000*192 u64 = 18432000 B (end ~31.2 MB)

// ---------------------------------------------------------------- prep: w (f32) -> f64
__global__ __launch_bounds__(256) void k_prepw(const float* __restrict__ w,
                                               double* __restrict__ w64) {
    int t = blockIdx.x * 256 + threadIdx.x;   // grid 2304 -> exactly 589824
    w64[t] = (double)w[t];
}

// ---------------------------------------------------------------- conv 3x3 256->256 (f64)
// No LDS. Weights read at block/loop-uniform addresses from const __restrict__
// global -> compiler emits s_load (SGPR operand to v_fma_f64). x stays f32
// (L2-resident), converted in-register.
__global__ __launch_bounds__(256) void k_conv3(const float* __restrict__ x,
                                               const double* __restrict__ w64,
                                               const float* __restrict__ b,
                                               double* __restrict__ h64) {
    const int p = blockIdx.x * 256 + threadIdx.x;
    const int o0 = blockIdx.y * 4;
    if (p >= NPIX) return;
    const int y = p / FEAT, xq = p % FEAT;
    double a0 = (double)b[o0+0], a1 = (double)b[o0+1];
    double a2 = (double)b[o0+2], a3 = (double)b[o0+3];
    int offs[9]; bool vm[9];
    #pragma unroll
    for (int kh = 0; kh < 3; ++kh) {
        #pragma unroll
        for (int kw = 0; kw < 3; ++kw) {
            int iy = y + kh - 1, ix = xq + kw - 1;
            bool v = ((unsigned)iy < (unsigned)FEAT) && ((unsigned)ix < (unsigned)FEAT);
            vm[kh*3+kw] = v;
            offs[kh*3+kw] = v ? iy*FEAT + ix : 0;
        }
    }
    const double* wb = w64 + o0 * 2304;        // uniform base
    #pragma unroll 2
    for (int ci = 0; ci < 256; ++ci) {
        const float* xb = x + ci * NPIX;
        double xv[9];
        #pragma unroll
        for (int k = 0; k < 9; ++k) {
            float t = xb[offs[k]];
            xv[k] = vm[k] ? (double)t : 0.0;
        }
        const double* wr = wb + ci * 9;        // uniform address -> s_load
        #pragma unroll
        for (int k = 0; k < 9; ++k) {
            a0 += xv[k] * wr[k];
            a1 += xv[k] * wr[k + 2304];
            a2 += xv[k] * wr[k + 4608];
            a3 += xv[k] * wr[k + 6912];
        }
    }
    h64[(o0+0)*NPIX + p] = a0;
    h64[(o0+1)*NPIX + p] = a1;
    h64[(o0+2)*NPIX + p] = a2;
    h64[(o0+3)*NPIX + p] = a3;
}

// ---------------------------------------------------------------- 1x1 convs (reg 36 + cls 18)
// Block = 256 px x 9 oc (grid.y = 6; groups 0..3 entirely reg, 4..5 entirely cls).
// h64 loaded once per ci and reused across the 9 oc; weights uniform s_load.
__global__ __launch_bounds__(256) void k_conv1(const double* __restrict__ h64,
                                               const float* __restrict__ regw,
                                               const float* __restrict__ regb,
                                               const float* __restrict__ clsw,
                                               const float* __restrict__ clsb,
                                               float* __restrict__ out,
                                               double* __restrict__ reg64,
                                               double* __restrict__ score64) {
    const int g = blockIdx.y;                  // 0..5
    const int p = blockIdx.x * 256 + threadIdx.x;
    if (p >= NPIX) return;
    const bool isreg = (g < 4);
    const float* wbase = isreg ? (regw + g * 9 * 256) : (clsw + (g - 4) * 9 * 256);
    const float* bbase = isreg ? (regb + g * 9)       : (clsb + (g - 4) * 9);
    double acc[9];
    #pragma unroll
    for (int j = 0; j < 9; ++j) acc[j] = (double)bbase[j];
    #pragma unroll 4
    for (int ci = 0; ci < 256; ++ci) {
        double h = h64[ci * NPIX + p];
        #pragma unroll
        for (int j = 0; j < 9; ++j)
            acc[j] += h * (double)wbase[j * 256 + ci];   // uniform -> s_load
    }
    #pragma unroll
    for (int j = 0; j < 9; ++j) {
        int oc = g * 9 + j;
        float v = (float)acc[j];
        if (isreg) {
            out[LOCS_OFF + p*36 + oc] = v;
            reg64[p*36 + oc] = acc[j];
        } else {
            int c = oc - 36;
            out[CLS_OFF  + p*18 + c] = v;
            out[CLS2_OFF + p*18 + c] = v;
            if (c & 1) {
                out[OBJ_OFF + p*9 + (c >> 1)] = v;
                score64[p*9 + (c >> 1)] = acc[j];
            }
        }
    }
}

// ---------------------------------------------------------------- decode + sort keys
__global__ __launch_bounds__(256) void k_decode(const double* __restrict__ reg64,
                                                const double* __restrict__ score64,
                                                double* __restrict__ roi64,
                                                u64* __restrict__ keys) {
    int t = blockIdx.x * 256 + threadIdx.x;    // grid 128 -> 32768
    if (t >= NANC) { keys[t] = ~0ull; return; }
    int pos = t / 9, a = t % 9;
    int py = pos / FEAT, px = pos % FEAT;
    int ri = a / 3, si = a % 3;
    double rat = (ri == 0) ? 0.5 : (ri == 1 ? 1.0 : 2.0);
    double scl = (si == 0) ? 4.0 : (si == 1 ? 8.0 : 16.0);
    double hA = 4.0 * scl * sqrt(rat);
    double wA = 4.0 * scl * sqrt(1.0 / rat);
    double cy0 = 4.0 * py + 2.0, cx0 = 4.0 * px + 2.0;
    // anchors go through f32 exactly like make_anchors().astype(float32)
    float y1f = (float)(cy0 - hA / 2.0), x1f = (float)(cx0 - wA / 2.0);
    float y2f = (float)(cy0 + hA / 2.0), x2f = (float)(cx0 + wA / 2.0);
    double ah = (double)y2f - (double)y1f, aw = (double)x2f - (double)x1f;
    double acy = (double)y1f + 0.5 * ah, acx = (double)x1f + 0.5 * aw;
    double l0 = reg64[4*t+0], l1 = reg64[4*t+1], l2 = reg64[4*t+2], l3 = reg64[4*t+3];
    double cy = l0 * ah + acy, cx = l1 * aw + acx;
    double hh = exp(l2) * ah,  ww = exp(l3) * aw;
    double r0 = fmin(fmax(cy - 0.5*hh, 0.0), 210.0);
    double r1 = fmin(fmax(cx - 0.5*ww, 0.0), 210.0);
    double r2 = fmin(fmax(cy + 0.5*hh, 0.0), 210.0);
    double r3 = fmin(fmax(cx + 0.5*ww, 0.0), 210.0);
    roi64[4*t+0] = r0; roi64[4*t+1] = r1; roi64[4*t+2] = r2; roi64[4*t+3] = r3;
    bool valid = (r2 - r0 >= 16.0) && (r3 - r1 >= 16.0);
    double m = valid ? score64[t] : -__builtin_huge_val();
    long long ll = __double_as_longlong(m);
    u64 u = (u64)ll;
    u64 mono = (ll < 0) ? ~u : (u ^ 0x8000000000000000ull); // ascending numeric
    keys[t] = ((~mono) & 0xFFFFFFFFFFFF0000ull) | (u64)t;   // asc key = desc score, stable
}

// ---------------------------------------------------------------- bitonic sort pieces
__global__ __launch_bounds__(1024) void k_sortA(u64* __restrict__ keys) {
    __shared__ u64 s[8192];                    // 64 KiB
    const int base = blockIdx.x * 8192;
    for (int t = threadIdx.x; t < 8192; t += 1024) s[t] = keys[base + t];
    __syncthreads();
    for (int k = 2; k <= 8192; k <<= 1) {
        for (int j = k >> 1; j > 0; j >>= 1) {
            for (int q = threadIdx.x; q < 4096; q += 1024) {
                int i = ((q & ~(j-1)) << 1) | (q & (j-1));
                int l = i | j;
                bool asc = (((base + i) & k) == 0);
                u64 A = s[i], B = s[l];
                bool sw = asc ? (A > B) : (A < B);
                if (sw) { s[i] = B; s[l] = A; }
            }
            __syncthreads();
        }
    }
    for (int t = threadIdx.x; t < 8192; t += 1024) keys[base + t] = s[t];
}

__global__ __launch_bounds__(1024) void k_sortB(u64* __restrict__ keys, int k) {
    __shared__ u64 s[8192];
    const int base = blockIdx.x * 8192;
    for (int t = threadIdx.x; t < 8192; t += 1024) s[t] = keys[base + t];
    __syncthreads();
    for (int j = 4096; j > 0; j >>= 1) {
        for (int q = threadIdx.x; q < 4096; q += 1024) {
            int i = ((q & ~(j-1)) << 1) | (q & (j-1));
            int l = i | j;
            bool asc = (((base + i) & k) == 0);
            u64 A = s[i], B = s[l];
            bool sw = asc ? (A > B) : (A < B);
            if (sw) { s[i] = B; s[l] = A; }
        }
        __syncthreads();
    }
    for (int t = threadIdx.x; t < 8192; t += 1024) keys[base + t] = s[t];
}

__global__ __launch_bounds__(256) void k_sortG(u64* __restrict__ keys, int k, int j) {
    int t = blockIdx.x * 256 + threadIdx.x;    // 16384 pairs
    int i = ((t & ~(j-1)) << 1) | (t & (j-1));
    int l = i | j;
    bool asc = ((i & k) == 0);
    u64 A = keys[i], B = keys[l];
    bool sw = asc ? (A > B) : (A < B);
    if (sw) { keys[i] = B; keys[l] = A; }
}

// ---------------------------------------------------------------- gather top-12000
__global__ __launch_bounds__(256) void k_gather(const u64* __restrict__ keys,
                                                const double* __restrict__ roi64,
                                                double* __restrict__ sbox,
                                                double* __restrict__ sarea,
                                                u64* __restrict__ suppinit) {
    int p = blockIdx.x * 256 + threadIdx.x;    // grid 48 -> 12288
    bool sup = true;
    if (p < PRE) {
        int idx = (int)(keys[p] & 0xFFFFull);
        double b0 = roi64[4*idx+0], b1 = roi64[4*idx+1];
        double b2 = roi64[4*idx+2], b3 = roi64[4*idx+3];
        sbox[4*p+0] = b0; sbox[4*p+1] = b1; sbox[4*p+2] = b2; sbox[4*p+3] = b3;
        sarea[p] = (b3 - b1 + 1.0) * (b2 - b0 + 1.0);
        sup = !((b2 - b0 >= 16.0) && (b3 - b1 >= 16.0));
    } else {
        sbox[4*p+0] = 0.0; sbox[4*p+1] = 0.0; sbox[4*p+2] = 0.0; sbox[4*p+3] = 0.0;
        sarea[p] = 1.0;
    }
    u64 ball = __ballot(sup);
    if ((threadIdx.x & 63) == 0) suppinit[p >> 6] = ball;
}

// ---------------------------------------------------------------- suppression bit matrix
__global__ __launch_bounds__(256) void k_mask(const double* __restrict__ sbox,
                                              const double* __restrict__ sarea,
                                              u64* __restrict__ mask) {
    const int jt = blockIdx.x, it = blockIdx.y;     // (12, 188)
    const int ib = it * 64, jb0 = jt * 1024;
    if (jb0 + 1023 <= ib) {                         // whole tile has j <= i -> zeros
        for (int t = threadIdx.x; t < 1024; t += 256) {
            int ti = t >> 4, w = t & 15;
            int i = ib + ti;
            if (i < PRE) mask[(size_t)i * ROWW + jt*16 + w] = 0ull;
        }
        return;
    }
    __shared__ double jbx[4096];
    __shared__ double jar[1024];
    for (int t = threadIdx.x; t < 4096; t += 256) jbx[t] = sbox[(size_t)jb0*4 + t];
    for (int t = threadIdx.x; t < 1024; t += 256) jar[t] = sarea[jb0 + t];
    __syncthreads();
    int ti = threadIdx.x >> 2;
    int i = ib + ti;
    if (i >= PRE) return;
    double iy1 = sbox[4*i+0], ix1 = sbox[4*i+1], iy2 = sbox[4*i+2], ix2 = sbox[4*i+3];
    double iar = sarea[i];
    for (int w = (threadIdx.x & 3); w < 16; w += 4) {
        u64 bits = 0ull;
        int q0 = w * 64;
        for (int l = 0; l < 64; ++l) {
            int q = q0 + l;
            double jy1 = jbx[4*q+0], jx1 = jbx[4*q+1], jy2 = jbx[4*q+2], jx2 = jbx[4*q+3];
            double yy1 = fmax(iy1, jy1), xx1 = fmax(ix1, jx1);
            double yy2 = fmin(iy2, jy2), xx2 = fmin(ix2, jx2);
            double iw = fmax(xx2 - xx1 + 1.0, 0.0);
            double ih = fmax(yy2 - yy1 + 1.0, 0.0);
            double inter = iw * ih;
            bool s = ((jb0 + q) > i) && (inter > 0.7 * (iar + jar[q] - inter));
            bits |= ((u64)s) << l;
        }
        mask[(size_t)i * ROWW + jt*16 + w] = bits;
    }
}

// ---------------------------------------------------------------- helpers for k_scan
__device__ inline u64 rdl64(u64 v, int l) {
    u32 lo = (u32)__builtin_amdgcn_readlane((int)(u32)v, l);
    u32 hi = (u32)__builtin_amdgcn_readlane((int)(u32)(v >> 32), l);
    return ((u64)hi << 32) | (u64)lo;
}
#define RFL64(lo, hi) ( ((u64)(u32)__builtin_amdgcn_readfirstlane((int)(hi)) << 32) \
                      | (u64)(u32)__builtin_amdgcn_readfirstlane((int)(lo)) )

// ---------------------------------------------------------------- NMS scan v3
__global__ __launch_bounds__(1024) void k_scan(const u64* __restrict__ mask,
                                               const u64* __restrict__ suppinit,
                                               const double* __restrict__ sbox,
                                               float* __restrict__ rois) {
    __shared__ u64 dbuf[2][4608];     // [buf][row*9 + w], 512 rows x 8(+1 pad) words
    __shared__ u32 keptLDS[POST];     // global sorted indices of kept boxes
    __shared__ u32 supp8[2][16];      // chunk supp words as u32 pairs
    __shared__ int rankS, doneS;
    const int tid = threadIdx.x;
    const u32* suppinit32 = (const u32*)suppinit;

    if (tid < 16) supp8[0][tid] = suppinit32[tid];
    if (tid == 0) { rankS = 0; doneS = 0; }
    for (int q = tid; q < 4096; q += 1024) {
        int r = q >> 3, w = q & 7;
        dbuf[0][r*9 + w] = (r < PRE) ? mask[(size_t)r * ROWW + w] : 0ull;
    }
    __syncthreads();

    for (int c = 0; c < 24; ++c) {
        const int nc = c + 1;
        const int cb = c & 1, nb = nc & 1;
        if (tid < 64) {
            // ---------- wave 0: scan chunk c ----------
            const int lane = tid;
            if (lane < 16 && nc < 24) supp8[nb][lane] = suppinit32[nc*16 + lane];
            u64 i0 = RFL64(supp8[cb][0],  supp8[cb][1]);
            u64 i1 = RFL64(supp8[cb][2],  supp8[cb][3]);
            u64 i2 = RFL64(supp8[cb][4],  supp8[cb][5]);
            u64 i3 = RFL64(supp8[cb][6],  supp8[cb][7]);
            u64 i4 = RFL64(supp8[cb][8],  supp8[cb][9]);
            u64 i5 = RFL64(supp8[cb][10], supp8[cb][11]);
            u64 i6 = RFL64(supp8[cb][12], supp8[cb][13]);
            u64 i7 = RFL64(supp8[cb][14], supp8[cb][15]);
            u64 a0=0,a1=0,a2=0,a3=0,a4=0,a5=0,a6=0,a7=0;
            int rk = __builtin_amdgcn_readfirstlane(rankS);
            bool dn = false;
#define GROUP(G)                                                                \
            if (!dn) {                                                          \
                u64 z = ~(i##G | a##G);                                         \
                if (z) {                                                        \
                    const u64* rowp = &dbuf[cb][(G*64 + lane)*9];               \
                    u64 r0=rowp[0],r1=rowp[1],r2=rowp[2],r3=rowp[3];            \
                    u64 r4=rowp[4],r5=rowp[5],r6=rowp[6],r7=rowp[7];            \
                    u64 keptm = 0;                                              \
                    while (z) {                                                 \
                        int bpos = (int)__builtin_ctzll(z);                     \
                        u64 q0=rdl64(r0,bpos), q1=rdl64(r1,bpos);               \
                        u64 q2=rdl64(r2,bpos), q3=rdl64(r3,bpos);               \
                        u64 q4=rdl64(r4,bpos), q5=rdl64(r5,bpos);               \
                        u64 q6=rdl64(r6,bpos), q7=rdl64(r7,bpos);               \
                        keptm |= (1ull << bpos);                                \
                        z &= ~(1ull << bpos) & ~q##G;                           \
                        a0|=q0; a1|=q1; a2|=q2; a3|=q3;                         \
                        a4|=q4; a5|=q5; a6|=q6; a7|=q7;                         \
                    }                                                           \
                    int pc = __builtin_popcountll(keptm);                       \
                    int navail = POST - rk;                                     \
                    int mylot = __builtin_amdgcn_mbcnt_hi((u32)(keptm >> 32),   \
                                 __builtin_amdgcn_mbcnt_lo((u32)keptm, 0));     \
                    if (((keptm >> lane) & 1) && mylot < navail)                \
                        keptLDS[rk + mylot] = (u32)(c*512 + G*64 + lane);       \
                    if (pc >= navail) { rk = POST; dn = true; }                 \
                    else rk += pc;                                              \
                }                                                               \
            }
            GROUP(0) GROUP(1) GROUP(2) GROUP(3)
            GROUP(4) GROUP(5) GROUP(6) GROUP(7)
#undef GROUP
            if (lane == 0) { rankS = rk; if (dn) doneS = 1; }
        } else if (nc < 24) {
            // ---------- waves 1..15: prefetch diag block of chunk nc ----------
            for (int q = tid - 64; q < 4096; q += 960) {
                int r = q >> 3, w = q & 7;
                int i = nc*512 + r;
                dbuf[nb][r*9 + w] = (i < PRE) ? mask[(size_t)i * ROWW + nc*8 + w] : 0ull;
            }
        }
        __syncthreads();
        if (doneS || nc >= 24) break;
        // ---------- JIT supp words for chunk nc: OR over all kept rows ----------
        {
            int rk = rankS;
            int w = tid & 7;
            u64 acc = 0;
            for (int k = tid >> 3; k < rk; k += 128)
                acc |= mask[(size_t)keptLDS[k] * ROWW + nc*8 + w];
            if (acc) {
                atomicOr(&supp8[nb][2*w],     (u32)acc);
                atomicOr(&supp8[nb][2*w + 1], (u32)(acc >> 32));
            }
        }
        __syncthreads();
    }
    __syncthreads();
    const int R = rankS;
    for (int r = tid; r < POST; r += 1024) {
        if (r < R) {
            int p = (int)keptLDS[r];
            rois[4*r+0] = (float)sbox[4*p+0];
            rois[4*r+1] = (float)sbox[4*p+1];
            rois[4*r+2] = (float)sbox[4*p+2];
            rois[4*r+3] = (float)sbox[4*p+3];
        } // else stays zero (memset)
    }
}

// ---------------------------------------------------------------- launcher
extern "C" void kernel_launch(void* const* d_in, const int* in_sizes, int n_in,
                              void* d_out, int out_size, void* d_ws, size_t ws_size,
                              hipStream_t stream) {
    const float* x    = (const float*)d_in[0];
    const float* w1   = (const float*)d_in[1];
    const float* b1   = (const float*)d_in[2];
    const float* regw = (const float*)d_in[3];
    const float* regb = (const float*)d_in[4];
    const float* clsw = (const float*)d_in[5];
    const float* clsb = (const float*)d_in[6];
    float* out = (float*)d_out;

    char* ws = (char*)d_ws;
    double* w64    = (double*)(ws + OFF_W64);
    double* h64    = (double*)(ws + OFF_H64);
    double* reg64  = (double*)(ws + OFF_REG64);
    double* sc64   = (double*)(ws + OFF_SC64);
    double* roi64  = (double*)(ws + OFF_ROI64);
    u64*    keys   = (u64*)   (ws + OFF_KEYS);
    double* sbox   = (double*)(ws + OFF_SBOX);
    double* sarea  = (double*)(ws + OFF_SAREA);
    u64*    supp0  = (u64*)   (ws + OFF_SUPP);
    u64*    maskp  = (u64*)   (ws + OFF_MASK);

    hipMemsetAsync(d_out, 0, 8000 * sizeof(float), stream);  // rois zero-padding

    k_prepw<<<2304, 256, 0, stream>>>(w1, w64);
    k_conv3<<<dim3(11, 64), 256, 0, stream>>>(x, w64, b1, h64);
    k_conv1<<<dim3(11, 6), 256, 0, stream>>>(h64, regw, regb, clsw, clsb, out, reg64, sc64);
    k_decode<<<128, 256, 0, stream>>>(reg64, sc64, roi64, keys);

    k_sortA<<<4, 1024, 0, stream>>>(keys);
    k_sortG<<<64, 256, 0, stream>>>(keys, 16384, 8192);
    k_sortB<<<4, 1024, 0, stream>>>(keys, 16384);
    k_sortG<<<64, 256, 0, stream>>>(keys, 32768, 16384);
    k_sortG<<<64, 256, 0, stream>>>(keys, 32768, 8192);
    k_sortB<<<4, 1024, 0, stream>>>(keys, 32768);

    k_gather<<<48, 256, 0, stream>>>(keys, roi64, sbox, sarea, supp0);
    k_mask<<<dim3(12, 188), 256, 0, stream>>>(sbox, sarea, maskp);
    k_scan<<<1, 1024, 0, stream>>>(maskp, supp0, sbox, out + ROIS_OFF);
}

// Round 6
// 674.334 us; speedup vs baseline: 1.6352x; 1.1393x over previous
//
#include <hip/hip_runtime.h>

typedef unsigned long long u64;
typedef unsigned int u32;

#define FEAT 52
#define NPIX 2704          // 52*52
#define NANC 24336         // NPIX*9
#define PRE  12000
#define POST 2000
#define ROWW 192           // u64 words per mask row (12288 bits = 24 chunks * 512)
#define PADW 54            // padded x row width
#define PADS 2916          // 54*54 per channel

// ---- d_out layout (float elements) ----
#define ROIS_OFF 0
#define LOCS_OFF 8000
#define CLS_OFF  105344
#define OBJ_OFF  154016
#define CLS2_OFF 178352

// ---- ws layout (byte offsets) ----
#define OFF_W64   0ull          //  589824 f64 (3x3 weights, [g][ci][k][4] layout)
#define OFF_H64   4718592ull    //  692224 f64
#define OFF_REG64 10256384ull   //   97344 f64
#define OFF_SC64  11035136ull   //   24336 f64
#define OFF_ROI64 11229824ull   //   97344 f64
#define OFF_KEYS  12008576ull   //   32768 u64
#define OFF_SBOX  12270720ull   //   49152 f64
#define OFF_SAREA 12663936ull   //   12288 f64
#define OFF_SUPP  12762240ull   //     192 u64
#define OFF_MASK  12763776ull   //   12000*192 u64 = 18432000 B (end ~31.2 MB)
// xpad (746496 f32 = 2985984 B) ALIASES the start of MASK: conv3 finishes
// before k_mask writes mask, so the overlap is safe and keeps ws under 32 MB.
#define OFF_XPAD  OFF_MASK

// ---------------------------------------------------------------- prep: pad x (f32)
__global__ __launch_bounds__(256) void k_prepx(const float* __restrict__ x,
                                               float* __restrict__ xpad) {
    int t = blockIdx.x * 256 + threadIdx.x;   // grid 2916 -> exactly 746496
    int ci = t / PADS, pos = t % PADS;
    int iy = pos / PADW, ix = pos % PADW;
    float v = 0.f;
    if (iy >= 1 && iy <= 52 && ix >= 1 && ix <= 52)
        v = x[ci * NPIX + (iy - 1) * FEAT + (ix - 1)];
    xpad[t] = v;
}

// ---------------------------------------------------------------- prep: w -> f64 [g][ci][k][4]
__global__ __launch_bounds__(256) void k_prepw(const float* __restrict__ w,
                                               double* __restrict__ w64) {
    int t = blockIdx.x * 256 + threadIdx.x;   // grid 2304 -> exactly 589824
    int j = t & 3;
    int r = t >> 2;
    int k = r % 9;
    int r2 = r / 9;
    int ci = r2 & 255;
    int g = r2 >> 8;
    w64[t] = (double)w[(((g * 4 + j) * 256) + ci) * 9 + k];
}

// ---------------------------------------------------------------- conv 3x3 256->256 (f64)
// Padded x (no masks, 9 immediate-offset loads off one base), weights at
// block/loop-uniform addresses in contiguous 288B/ci blocks -> s_load runs.
__global__ __launch_bounds__(256) void k_conv3(const float* __restrict__ xpad,
                                               const double* __restrict__ w64,
                                               const float* __restrict__ b,
                                               double* __restrict__ h64) {
    const int p = blockIdx.x * 256 + threadIdx.x;
    const int o0 = blockIdx.y * 4;
    if (p >= NPIX) return;
    const int y = p / FEAT, xq = p % FEAT;
    double a0 = (double)b[o0+0], a1 = (double)b[o0+1];
    double a2 = (double)b[o0+2], a3 = (double)b[o0+3];
    const float* xb = xpad + y * PADW + xq;       // tap (kh,kw) at xb[kh*54+kw]
    const double* wb = w64 + (size_t)blockIdx.y * 9216;   // uniform base
    #pragma unroll 2
    for (int ci = 0; ci < 256; ++ci) {
        float f0 = xb[0],   f1 = xb[1],   f2 = xb[2];
        float f3 = xb[54],  f4 = xb[55],  f5 = xb[56];
        float f6 = xb[108], f7 = xb[109], f8 = xb[110];
        double xv[9];
        xv[0]=(double)f0; xv[1]=(double)f1; xv[2]=(double)f2;
        xv[3]=(double)f3; xv[4]=(double)f4; xv[5]=(double)f5;
        xv[6]=(double)f6; xv[7]=(double)f7; xv[8]=(double)f8;
        const double* wr = wb + ci * 36;          // uniform -> s_load_dwordx16
        #pragma unroll
        for (int k = 0; k < 9; ++k) {
            a0 += xv[k] * wr[4*k+0];
            a1 += xv[k] * wr[4*k+1];
            a2 += xv[k] * wr[4*k+2];
            a3 += xv[k] * wr[4*k+3];
        }
        xb += PADS;
    }
    h64[(o0+0)*NPIX + p] = a0;
    h64[(o0+1)*NPIX + p] = a1;
    h64[(o0+2)*NPIX + p] = a2;
    h64[(o0+3)*NPIX + p] = a3;
}

// ---------------------------------------------------------------- 1x1 convs (reg 36 + cls 18)
// 64-thread blocks, grid (43,6) = 258 blocks: 1 px x 9 oc per thread.
__global__ __launch_bounds__(64) void k_conv1(const double* __restrict__ h64,
                                              const float* __restrict__ regw,
                                              const float* __restrict__ regb,
                                              const float* __restrict__ clsw,
                                              const float* __restrict__ clsb,
                                              float* __restrict__ out,
                                              double* __restrict__ reg64,
                                              double* __restrict__ score64) {
    const int g = blockIdx.y;                  // 0..5
    const int p = blockIdx.x * 64 + threadIdx.x;
    if (p >= NPIX) return;
    const bool isreg = (g < 4);
    const float* wbase = isreg ? (regw + g * 9 * 256) : (clsw + (g - 4) * 9 * 256);
    const float* bbase = isreg ? (regb + g * 9)       : (clsb + (g - 4) * 9);
    double acc[9];
    #pragma unroll
    for (int j = 0; j < 9; ++j) acc[j] = (double)bbase[j];
    #pragma unroll 4
    for (int ci = 0; ci < 256; ++ci) {
        double h = h64[ci * NPIX + p];
        #pragma unroll
        for (int j = 0; j < 9; ++j)
            acc[j] += h * (double)wbase[j * 256 + ci];   // uniform -> s_load
    }
    #pragma unroll
    for (int j = 0; j < 9; ++j) {
        int oc = g * 9 + j;
        float v = (float)acc[j];
        if (isreg) {
            out[LOCS_OFF + p*36 + oc] = v;
            reg64[p*36 + oc] = acc[j];
        } else {
            int c = oc - 36;
            out[CLS_OFF  + p*18 + c] = v;
            out[CLS2_OFF + p*18 + c] = v;
            if (c & 1) {
                out[OBJ_OFF + p*9 + (c >> 1)] = v;
                score64[p*9 + (c >> 1)] = acc[j];
            }
        }
    }
}

// ---------------------------------------------------------------- decode + sort keys
__global__ __launch_bounds__(256) void k_decode(const double* __restrict__ reg64,
                                                const double* __restrict__ score64,
                                                double* __restrict__ roi64,
                                                u64* __restrict__ keys) {
    int t = blockIdx.x * 256 + threadIdx.x;    // grid 128 -> 32768
    if (t >= NANC) { keys[t] = ~0ull; return; }
    int pos = t / 9, a = t % 9;
    int py = pos / FEAT, px = pos % FEAT;
    int ri = a / 3, si = a % 3;
    double rat = (ri == 0) ? 0.5 : (ri == 1 ? 1.0 : 2.0);
    double scl = (si == 0) ? 4.0 : (si == 1 ? 8.0 : 16.0);
    double hA = 4.0 * scl * sqrt(rat);
    double wA = 4.0 * scl * sqrt(1.0 / rat);
    double cy0 = 4.0 * py + 2.0, cx0 = 4.0 * px + 2.0;
    // anchors go through f32 exactly like make_anchors().astype(float32)
    float y1f = (float)(cy0 - hA / 2.0), x1f = (float)(cx0 - wA / 2.0);
    float y2f = (float)(cy0 + hA / 2.0), x2f = (float)(cx0 + wA / 2.0);
    double ah = (double)y2f - (double)y1f, aw = (double)x2f - (double)x1f;
    double acy = (double)y1f + 0.5 * ah, acx = (double)x1f + 0.5 * aw;
    double l0 = reg64[4*t+0], l1 = reg64[4*t+1], l2 = reg64[4*t+2], l3 = reg64[4*t+3];
    double cy = l0 * ah + acy, cx = l1 * aw + acx;
    double hh = exp(l2) * ah,  ww = exp(l3) * aw;
    double r0 = fmin(fmax(cy - 0.5*hh, 0.0), 210.0);
    double r1 = fmin(fmax(cx - 0.5*ww, 0.0), 210.0);
    double r2 = fmin(fmax(cy + 0.5*hh, 0.0), 210.0);
    double r3 = fmin(fmax(cx + 0.5*ww, 0.0), 210.0);
    roi64[4*t+0] = r0; roi64[4*t+1] = r1; roi64[4*t+2] = r2; roi64[4*t+3] = r3;
    bool valid = (r2 - r0 >= 16.0) && (r3 - r1 >= 16.0);
    double m = valid ? score64[t] : -__builtin_huge_val();
    long long ll = __double_as_longlong(m);
    u64 u = (u64)ll;
    u64 mono = (ll < 0) ? ~u : (u ^ 0x8000000000000000ull); // ascending numeric
    keys[t] = ((~mono) & 0xFFFFFFFFFFFF0000ull) | (u64)t;   // asc key = desc score, stable
}

// ---------------------------------------------------------------- bitonic sort pieces
__global__ __launch_bounds__(1024) void k_sortA(u64* __restrict__ keys) {
    __shared__ u64 s[8192];                    // 64 KiB
    const int base = blockIdx.x * 8192;
    for (int t = threadIdx.x; t < 8192; t += 1024) s[t] = keys[base + t];
    __syncthreads();
    for (int k = 2; k <= 8192; k <<= 1) {
        for (int j = k >> 1; j > 0; j >>= 1) {
            for (int q = threadIdx.x; q < 4096; q += 1024) {
                int i = ((q & ~(j-1)) << 1) | (q & (j-1));
                int l = i | j;
                bool asc = (((base + i) & k) == 0);
                u64 A = s[i], B = s[l];
                bool sw = asc ? (A > B) : (A < B);
                if (sw) { s[i] = B; s[l] = A; }
            }
            __syncthreads();
        }
    }
    for (int t = threadIdx.x; t < 8192; t += 1024) keys[base + t] = s[t];
}

__global__ __launch_bounds__(1024) void k_sortB(u64* __restrict__ keys, int k) {
    __shared__ u64 s[8192];
    const int base = blockIdx.x * 8192;
    for (int t = threadIdx.x; t < 8192; t += 1024) s[t] = keys[base + t];
    __syncthreads();
    for (int j = 4096; j > 0; j >>= 1) {
        for (int q = threadIdx.x; q < 4096; q += 1024) {
            int i = ((q & ~(j-1)) << 1) | (q & (j-1));
            int l = i | j;
            bool asc = (((base + i) & k) == 0);
            u64 A = s[i], B = s[l];
            bool sw = asc ? (A > B) : (A < B);
            if (sw) { s[i] = B; s[l] = A; }
        }
        __syncthreads();
    }
    for (int t = threadIdx.x; t < 8192; t += 1024) keys[base + t] = s[t];
}

__global__ __launch_bounds__(256) void k_sortG(u64* __restrict__ keys, int k, int j) {
    int t = blockIdx.x * 256 + threadIdx.x;    // 16384 pairs
    int i = ((t & ~(j-1)) << 1) | (t & (j-1));
    int l = i | j;
    bool asc = ((i & k) == 0);
    u64 A = keys[i], B = keys[l];
    bool sw = asc ? (A > B) : (A < B);
    if (sw) { keys[i] = B; keys[l] = A; }
}

// ---------------------------------------------------------------- gather top-12000
__global__ __launch_bounds__(256) void k_gather(const u64* __restrict__ keys,
                                                const double* __restrict__ roi64,
                                                double* __restrict__ sbox,
                                                double* __restrict__ sarea,
                                                u64* __restrict__ suppinit) {
    int p = blockIdx.x * 256 + threadIdx.x;    // grid 48 -> 12288
    bool sup = true;
    if (p < PRE) {
        int idx = (int)(keys[p] & 0xFFFFull);
        double b0 = roi64[4*idx+0], b1 = roi64[4*idx+1];
        double b2 = roi64[4*idx+2], b3 = roi64[4*idx+3];
        sbox[4*p+0] = b0; sbox[4*p+1] = b1; sbox[4*p+2] = b2; sbox[4*p+3] = b3;
        sarea[p] = (b3 - b1 + 1.0) * (b2 - b0 + 1.0);
        sup = !((b2 - b0 >= 16.0) && (b3 - b1 >= 16.0));
    } else {
        sbox[4*p+0] = 0.0; sbox[4*p+1] = 0.0; sbox[4*p+2] = 0.0; sbox[4*p+3] = 0.0;
        sarea[p] = 1.0;
    }
    u64 ball = __ballot(sup);
    if ((threadIdx.x & 63) == 0) suppinit[p >> 6] = ball;
}

// ---------------------------------------------------------------- suppression bit matrix
__global__ __launch_bounds__(256) void k_mask(const double* __restrict__ sbox,
                                              const double* __restrict__ sarea,
                                              u64* __restrict__ mask) {
    const int jt = blockIdx.x, it = blockIdx.y;     // (12, 188)
    const int ib = it * 64, jb0 = jt * 1024;
    if (jb0 + 1023 <= ib) {                         // whole tile has j <= i -> zeros
        for (int t = threadIdx.x; t < 1024; t += 256) {
            int ti = t >> 4, w = t & 15;
            int i = ib + ti;
            if (i < PRE) mask[(size_t)i * ROWW + jt*16 + w] = 0ull;
        }
        return;
    }
    __shared__ double jbx[4096];
    __shared__ double jar[1024];
    for (int t = threadIdx.x; t < 4096; t += 256) jbx[t] = sbox[(size_t)jb0*4 + t];
    for (int t = threadIdx.x; t < 1024; t += 256) jar[t] = sarea[jb0 + t];
    __syncthreads();
    int ti = threadIdx.x >> 2;
    int i = ib + ti;
    if (i >= PRE) return;
    double iy1 = sbox[4*i+0], ix1 = sbox[4*i+1], iy2 = sbox[4*i+2], ix2 = sbox[4*i+3];
    double iar = sarea[i];
    for (int w = (threadIdx.x & 3); w < 16; w += 4) {
        u64 bits = 0ull;
        int q0 = w * 64;
        for (int l = 0; l < 64; ++l) {
            int q = q0 + l;
            double jy1 = jbx[4*q+0], jx1 = jbx[4*q+1], jy2 = jbx[4*q+2], jx2 = jbx[4*q+3];
            double yy1 = fmax(iy1, jy1), xx1 = fmax(ix1, jx1);
            double yy2 = fmin(iy2, jy2), xx2 = fmin(ix2, jx2);
            double iw = fmax(xx2 - xx1 + 1.0, 0.0);
            double ih = fmax(yy2 - yy1 + 1.0, 0.0);
            double inter = iw * ih;
            bool s = ((jb0 + q) > i) && (inter > 0.7 * (iar + jar[q] - inter));
            bits |= ((u64)s) << l;
        }
        mask[(size_t)i * ROWW + jt*16 + w] = bits;
    }
}

// ---------------------------------------------------------------- helpers for k_scan
__device__ inline u64 rdl64(u64 v, int l) {
    u32 lo = (u32)__builtin_amdgcn_readlane((int)(u32)v, l);
    u32 hi = (u32)__builtin_amdgcn_readlane((int)(u32)(v >> 32), l);
    return ((u64)hi << 32) | (u64)lo;
}
#define RFL64(lo, hi) ( ((u64)(u32)__builtin_amdgcn_readfirstlane((int)(hi)) << 32) \
                      | (u64)(u32)__builtin_amdgcn_readfirstlane((int)(lo)) )

// ---------------------------------------------------------------- NMS scan v3
__global__ __launch_bounds__(1024) void k_scan(const u64* __restrict__ mask,
                                               const u64* __restrict__ suppinit,
                                               const double* __restrict__ sbox,
                                               float* __restrict__ rois) {
    __shared__ u64 dbuf[2][4608];     // [buf][row*9 + w], 512 rows x 8(+1 pad) words
    __shared__ u32 keptLDS[POST];     // global sorted indices of kept boxes
    __shared__ u32 supp8[2][16];      // chunk supp words as u32 pairs
    __shared__ int rankS, doneS;
    const int tid = threadIdx.x;
    const u32* suppinit32 = (const u32*)suppinit;

    if (tid < 16) supp8[0][tid] = suppinit32[tid];
    if (tid == 0) { rankS = 0; doneS = 0; }
    for (int q = tid; q < 4096; q += 1024) {
        int r = q >> 3, w = q & 7;
        dbuf[0][r*9 + w] = (r < PRE) ? mask[(size_t)r * ROWW + w] : 0ull;
    }
    __syncthreads();

    for (int c = 0; c < 24; ++c) {
        const int nc = c + 1;
        const int cb = c & 1, nb = nc & 1;
        if (tid < 64) {
            // ---------- wave 0: scan chunk c ----------
            const int lane = tid;
            if (lane < 16 && nc < 24) supp8[nb][lane] = suppinit32[nc*16 + lane];
            u64 i0 = RFL64(supp8[cb][0],  supp8[cb][1]);
            u64 i1 = RFL64(supp8[cb][2],  supp8[cb][3]);
            u64 i2 = RFL64(supp8[cb][4],  supp8[cb][5]);
            u64 i3 = RFL64(supp8[cb][6],  supp8[cb][7]);
            u64 i4 = RFL64(supp8[cb][8],  supp8[cb][9]);
            u64 i5 = RFL64(supp8[cb][10], supp8[cb][11]);
            u64 i6 = RFL64(supp8[cb][12], supp8[cb][13]);
            u64 i7 = RFL64(supp8[cb][14], supp8[cb][15]);
            u64 a0=0,a1=0,a2=0,a3=0,a4=0,a5=0,a6=0,a7=0;
            int rk = __builtin_amdgcn_readfirstlane(rankS);
            bool dn = false;
#define GROUP(G)                                                                \
            if (!dn) {                                                          \
                u64 z = ~(i##G | a##G);                                         \
                if (z) {                                                        \
                    const u64* rowp = &dbuf[cb][(G*64 + lane)*9];               \
                    u64 r0=rowp[0],r1=rowp[1],r2=rowp[2],r3=rowp[3];            \
                    u64 r4=rowp[4],r5=rowp[5],r6=rowp[6],r7=rowp[7];            \
                    u64 keptm = 0;                                              \
                    while (z) {                                                 \
                        int bpos = (int)__builtin_ctzll(z);                     \
                        u64 q0=rdl64(r0,bpos), q1=rdl64(r1,bpos);               \
                        u64 q2=rdl64(r2,bpos), q3=rdl64(r3,bpos);               \
                        u64 q4=rdl64(r4,bpos), q5=rdl64(r5,bpos);               \
                        u64 q6=rdl64(r6,bpos), q7=rdl64(r7,bpos);               \
                        keptm |= (1ull << bpos);                                \
                        z &= ~(1ull << bpos) & ~q##G;                           \
                        a0|=q0; a1|=q1; a2|=q2; a3|=q3;                         \
                        a4|=q4; a5|=q5; a6|=q6; a7|=q7;                         \
                    }                                                           \
                    int pc = __builtin_popcountll(keptm);                       \
                    int navail = POST - rk;                                     \
                    int mylot = __builtin_amdgcn_mbcnt_hi((u32)(keptm >> 32),   \
                                 __builtin_amdgcn_mbcnt_lo((u32)keptm, 0));     \
                    if (((keptm >> lane) & 1) && mylot < navail)                \
                        keptLDS[rk + mylot] = (u32)(c*512 + G*64 + lane);       \
                    if (pc >= navail) { rk = POST; dn = true; }                 \
                    else rk += pc;                                              \
                }                                                               \
            }
            GROUP(0) GROUP(1) GROUP(2) GROUP(3)
            GROUP(4) GROUP(5) GROUP(6) GROUP(7)
#undef GROUP
            if (lane == 0) { rankS = rk; if (dn) doneS = 1; }
        } else if (nc < 24) {
            // ---------- waves 1..15: prefetch diag block of chunk nc ----------
            for (int q = tid - 64; q < 4096; q += 960) {
                int r = q >> 3, w = q & 7;
                int i = nc*512 + r;
                dbuf[nb][r*9 + w] = (i < PRE) ? mask[(size_t)i * ROWW + nc*8 + w] : 0ull;
            }
        }
        __syncthreads();
        if (doneS || nc >= 24) break;
        // ---------- JIT supp words for chunk nc: OR over all kept rows ----------
        {
            int rk = rankS;
            int w = tid & 7;
            u64 acc = 0;
            for (int k = tid >> 3; k < rk; k += 128)
                acc |= mask[(size_t)keptLDS[k] * ROWW + nc*8 + w];
            if (acc) {
                atomicOr(&supp8[nb][2*w],     (u32)acc);
                atomicOr(&supp8[nb][2*w + 1], (u32)(acc >> 32));
            }
        }
        __syncthreads();
    }
    __syncthreads();
    const int R = rankS;
    for (int r = tid; r < POST; r += 1024) {
        if (r < R) {
            int p = (int)keptLDS[r];
            rois[4*r+0] = (float)sbox[4*p+0];
            rois[4*r+1] = (float)sbox[4*p+1];
            rois[4*r+2] = (float)sbox[4*p+2];
            rois[4*r+3] = (float)sbox[4*p+3];
        } // else stays zero (memset)
    }
}

// ---------------------------------------------------------------- launcher
extern "C" void kernel_launch(void* const* d_in, const int* in_sizes, int n_in,
                              void* d_out, int out_size, void* d_ws, size_t ws_size,
                              hipStream_t stream) {
    const float* x    = (const float*)d_in[0];
    const float* w1   = (const float*)d_in[1];
    const float* b1   = (const float*)d_in[2];
    const float* regw = (const float*)d_in[3];
    const float* regb = (const float*)d_in[4];
    const float* clsw = (const float*)d_in[5];
    const float* clsb = (const float*)d_in[6];
    float* out = (float*)d_out;

    char* ws = (char*)d_ws;
    double* w64    = (double*)(ws + OFF_W64);
    double* h64    = (double*)(ws + OFF_H64);
    double* reg64  = (double*)(ws + OFF_REG64);
    double* sc64   = (double*)(ws + OFF_SC64);
    double* roi64  = (double*)(ws + OFF_ROI64);
    u64*    keys   = (u64*)   (ws + OFF_KEYS);
    double* sbox   = (double*)(ws + OFF_SBOX);
    double* sarea  = (double*)(ws + OFF_SAREA);
    u64*    supp0  = (u64*)   (ws + OFF_SUPP);
    u64*    maskp  = (u64*)   (ws + OFF_MASK);
    float*  xpad   = (float*) (ws + OFF_XPAD);   // aliases mask region (safe: used before k_mask)

    hipMemsetAsync(d_out, 0, 8000 * sizeof(float), stream);  // rois zero-padding

    k_prepx<<<2916, 256, 0, stream>>>(x, xpad);
    k_prepw<<<2304, 256, 0, stream>>>(w1, w64);
    k_conv3<<<dim3(11, 64), 256, 0, stream>>>(xpad, w64, b1, h64);
    k_conv1<<<dim3(43, 6), 64, 0, stream>>>(h64, regw, regb, clsw, clsb, out, reg64, sc64);
    k_decode<<<128, 256, 0, stream>>>(reg64, sc64, roi64, keys);

    k_sortA<<<4, 1024, 0, stream>>>(keys);
    k_sortG<<<64, 256, 0, stream>>>(keys, 16384, 8192);
    k_sortB<<<4, 1024, 0, stream>>>(keys, 16384);
    k_sortG<<<64, 256, 0, stream>>>(keys, 32768, 16384);
    k_sortG<<<64, 256, 0, stream>>>(keys, 32768, 8192);
    k_sortB<<<4, 1024, 0, stream>>>(keys, 32768);

    k_gather<<<48, 256, 0, stream>>>(keys, roi64, sbox, sarea, supp0);
    k_mask<<<dim3(12, 188), 256, 0, stream>>>(sbox, sarea, maskp);
    k_scan<<<1, 1024, 0, stream>>>(maskp, supp0, sbox, out + ROIS_OFF);
}

// Round 7
// 635.078 us; speedup vs baseline: 1.7362x; 1.0618x over previous
//
#include <hip/hip_runtime.h>

typedef unsigned long long u64;
typedef unsigned int u32;

#define FEAT 52
#define NPIX 2704          // 52*52
#define NANC 24336         // NPIX*9
#define PRE  12000
#define POST 2000
#define ROWW 192           // u64 words per mask row (12288 bits = 24 chunks * 512)
#define PADW 54            // padded x row width
#define PADS 2916          // 54*54 per channel

// ---- d_out layout (float elements) ----
#define ROIS_OFF 0
#define LOCS_OFF 8000
#define CLS_OFF  105344
#define OBJ_OFF  154016
#define CLS2_OFF 178352

// ---- ws layout (byte offsets) ----
#define OFF_W64   0ull          //  589824 f64 (3x3 weights, [g][ci][k][4] layout)
#define OFF_H64   4718592ull    //  692224 f64 (half 0 partial, includes bias)
#define OFF_REG64 10256384ull   //   97344 f64
#define OFF_SC64  11035136ull   //   24336 f64
#define OFF_ROI64 11229824ull   //   97344 f64
#define OFF_KEYS  12008576ull   //   32768 u64
#define OFF_SBOX  12270720ull   //   49152 f64
#define OFF_SAREA 12663936ull   //   12288 f64
#define OFF_SUPP  12762240ull   //     192 u64
#define OFF_MASK  12763776ull   //   12000*192 u64 = 18432000 B (end ~31.2 MB)
// xpad (2985984 B) and h64b (5537792 B) ALIAS the mask region: both are
// consumed by conv3/conv1 which finish before k_mask writes mask. 8.5 MB < 18.4 MB.
#define OFF_XPAD  OFF_MASK
#define OFF_H64B  (OFF_MASK + 2985984ull)

// ---------------------------------------------------------------- prep: pad x (f32)
__global__ __launch_bounds__(256) void k_prepx(const float* __restrict__ x,
                                               float* __restrict__ xpad) {
    int t = blockIdx.x * 256 + threadIdx.x;   // grid 2916 -> exactly 746496
    int ci = t / PADS, pos = t % PADS;
    int iy = pos / PADW, ix = pos % PADW;
    float v = 0.f;
    if (iy >= 1 && iy <= 52 && ix >= 1 && ix <= 52)
        v = x[ci * NPIX + (iy - 1) * FEAT + (ix - 1)];
    xpad[t] = v;
}

// ---------------------------------------------------------------- prep: w -> f64 [g][ci][k][4]
__global__ __launch_bounds__(256) void k_prepw(const float* __restrict__ w,
                                               double* __restrict__ w64) {
    int t = blockIdx.x * 256 + threadIdx.x;   // grid 2304 -> exactly 589824
    int j = t & 3;
    int r = t >> 2;
    int k = r % 9;
    int r2 = r / 9;
    int ci = r2 & 255;
    int g = r2 >> 8;
    w64[t] = (double)w[(((g * 4 + j) * 256) + ci) * 9 + k];
}

// ---------------------------------------------------------------- conv 3x3 256->256 (f64)
// grid (11, 64, 2): z = ci-half. Both halves run concurrently in one dispatch
// (5.5 waves/SIMD vs 2.75) writing partial sums; conv1 adds them. Padded x
// (no masks), weights contiguous 288B/ci at uniform addresses -> s_load.
__global__ __launch_bounds__(256) void k_conv3(const float* __restrict__ xpad,
                                               const double* __restrict__ w64,
                                               const float* __restrict__ b,
                                               double* __restrict__ h64,
                                               double* __restrict__ h64b) {
    const int p = blockIdx.x * 256 + threadIdx.x;
    const int o0 = blockIdx.y * 4;
    const int half = blockIdx.z;              // 0: ci 0..127 (+bias), 1: ci 128..255
    if (p >= NPIX) return;
    const int y = p / FEAT, xq = p % FEAT;
    double a0, a1, a2, a3;
    if (half == 0) {
        a0 = (double)b[o0+0]; a1 = (double)b[o0+1];
        a2 = (double)b[o0+2]; a3 = (double)b[o0+3];
    } else {
        a0 = a1 = a2 = a3 = 0.0;
    }
    const int c0 = half << 7;
    const float* xb = xpad + (size_t)c0 * PADS + y * PADW + xq;
    const double* wb = w64 + (size_t)blockIdx.y * 9216 + c0 * 36;
    #pragma unroll 2
    for (int ci = 0; ci < 128; ++ci) {
        float f0 = xb[0],   f1 = xb[1],   f2 = xb[2];
        float f3 = xb[54],  f4 = xb[55],  f5 = xb[56];
        float f6 = xb[108], f7 = xb[109], f8 = xb[110];
        double xv[9];
        xv[0]=(double)f0; xv[1]=(double)f1; xv[2]=(double)f2;
        xv[3]=(double)f3; xv[4]=(double)f4; xv[5]=(double)f5;
        xv[6]=(double)f6; xv[7]=(double)f7; xv[8]=(double)f8;
        const double* wr = wb + ci * 36;          // uniform -> s_load
        #pragma unroll
        for (int k = 0; k < 9; ++k) {
            a0 += xv[k] * wr[4*k+0];
            a1 += xv[k] * wr[4*k+1];
            a2 += xv[k] * wr[4*k+2];
            a3 += xv[k] * wr[4*k+3];
        }
        xb += PADS;
    }
    double* ho = (half == 0) ? h64 : h64b;
    ho[(o0+0)*NPIX + p] = a0;
    ho[(o0+1)*NPIX + p] = a1;
    ho[(o0+2)*NPIX + p] = a2;
    ho[(o0+3)*NPIX + p] = a3;
}

// ---------------------------------------------------------------- 1x1 convs (reg 36 + cls 18)
// 64-thread blocks, grid (43,6): 1 px x 9 oc per thread. h = h64 + h64b.
__global__ __launch_bounds__(64) void k_conv1(const double* __restrict__ h64,
                                              const double* __restrict__ h64b,
                                              const float* __restrict__ regw,
                                              const float* __restrict__ regb,
                                              const float* __restrict__ clsw,
                                              const float* __restrict__ clsb,
                                              float* __restrict__ out,
                                              double* __restrict__ reg64,
                                              double* __restrict__ score64) {
    const int g = blockIdx.y;                  // 0..5
    const int p = blockIdx.x * 64 + threadIdx.x;
    if (p >= NPIX) return;
    const bool isreg = (g < 4);
    const float* wbase = isreg ? (regw + g * 9 * 256) : (clsw + (g - 4) * 9 * 256);
    const float* bbase = isreg ? (regb + g * 9)       : (clsb + (g - 4) * 9);
    double acc[9];
    #pragma unroll
    for (int j = 0; j < 9; ++j) acc[j] = (double)bbase[j];
    #pragma unroll 4
    for (int ci = 0; ci < 256; ++ci) {
        double h = h64[ci * NPIX + p] + h64b[ci * NPIX + p];
        #pragma unroll
        for (int j = 0; j < 9; ++j)
            acc[j] += h * (double)wbase[j * 256 + ci];   // uniform -> s_load
    }
    #pragma unroll
    for (int j = 0; j < 9; ++j) {
        int oc = g * 9 + j;
        float v = (float)acc[j];
        if (isreg) {
            out[LOCS_OFF + p*36 + oc] = v;
            reg64[p*36 + oc] = acc[j];
        } else {
            int c = oc - 36;
            out[CLS_OFF  + p*18 + c] = v;
            out[CLS2_OFF + p*18 + c] = v;
            if (c & 1) {
                out[OBJ_OFF + p*9 + (c >> 1)] = v;
                score64[p*9 + (c >> 1)] = acc[j];
            }
        }
    }
}

// ---------------------------------------------------------------- decode + sort keys
__global__ __launch_bounds__(256) void k_decode(const double* __restrict__ reg64,
                                                const double* __restrict__ score64,
                                                double* __restrict__ roi64,
                                                u64* __restrict__ keys) {
    int t = blockIdx.x * 256 + threadIdx.x;    // grid 128 -> 32768
    if (t >= NANC) { keys[t] = ~0ull; return; }
    int pos = t / 9, a = t % 9;
    int py = pos / FEAT, px = pos % FEAT;
    int ri = a / 3, si = a % 3;
    double rat = (ri == 0) ? 0.5 : (ri == 1 ? 1.0 : 2.0);
    double scl = (si == 0) ? 4.0 : (si == 1 ? 8.0 : 16.0);
    double hA = 4.0 * scl * sqrt(rat);
    double wA = 4.0 * scl * sqrt(1.0 / rat);
    double cy0 = 4.0 * py + 2.0, cx0 = 4.0 * px + 2.0;
    // anchors go through f32 exactly like make_anchors().astype(float32)
    float y1f = (float)(cy0 - hA / 2.0), x1f = (float)(cx0 - wA / 2.0);
    float y2f = (float)(cy0 + hA / 2.0), x2f = (float)(cx0 + wA / 2.0);
    double ah = (double)y2f - (double)y1f, aw = (double)x2f - (double)x1f;
    double acy = (double)y1f + 0.5 * ah, acx = (double)x1f + 0.5 * aw;
    double l0 = reg64[4*t+0], l1 = reg64[4*t+1], l2 = reg64[4*t+2], l3 = reg64[4*t+3];
    double cy = l0 * ah + acy, cx = l1 * aw + acx;
    double hh = exp(l2) * ah,  ww = exp(l3) * aw;
    double r0 = fmin(fmax(cy - 0.5*hh, 0.0), 210.0);
    double r1 = fmin(fmax(cx - 0.5*ww, 0.0), 210.0);
    double r2 = fmin(fmax(cy + 0.5*hh, 0.0), 210.0);
    double r3 = fmin(fmax(cx + 0.5*ww, 0.0), 210.0);
    roi64[4*t+0] = r0; roi64[4*t+1] = r1; roi64[4*t+2] = r2; roi64[4*t+3] = r3;
    bool valid = (r2 - r0 >= 16.0) && (r3 - r1 >= 16.0);
    double m = valid ? score64[t] : -__builtin_huge_val();
    long long ll = __double_as_longlong(m);
    u64 u = (u64)ll;
    u64 mono = (ll < 0) ? ~u : (u ^ 0x8000000000000000ull); // ascending numeric
    keys[t] = ((~mono) & 0xFFFFFFFFFFFF0000ull) | (u64)t;   // asc key = desc score, stable
}

// ---------------------------------------------------------------- bitonic sort pieces
__global__ __launch_bounds__(1024) void k_sortA(u64* __restrict__ keys) {
    __shared__ u64 s[8192];                    // 64 KiB
    const int base = blockIdx.x * 8192;
    for (int t = threadIdx.x; t < 8192; t += 1024) s[t] = keys[base + t];
    __syncthreads();
    for (int k = 2; k <= 8192; k <<= 1) {
        for (int j = k >> 1; j > 0; j >>= 1) {
            for (int q = threadIdx.x; q < 4096; q += 1024) {
                int i = ((q & ~(j-1)) << 1) | (q & (j-1));
                int l = i | j;
                bool asc = (((base + i) & k) == 0);
                u64 A = s[i], B = s[l];
                bool sw = asc ? (A > B) : (A < B);
                if (sw) { s[i] = B; s[l] = A; }
            }
            __syncthreads();
        }
    }
    for (int t = threadIdx.x; t < 8192; t += 1024) keys[base + t] = s[t];
}

__global__ __launch_bounds__(1024) void k_sortB(u64* __restrict__ keys, int k) {
    __shared__ u64 s[8192];
    const int base = blockIdx.x * 8192;
    for (int t = threadIdx.x; t < 8192; t += 1024) s[t] = keys[base + t];
    __syncthreads();
    for (int j = 4096; j > 0; j >>= 1) {
        for (int q = threadIdx.x; q < 4096; q += 1024) {
            int i = ((q & ~(j-1)) << 1) | (q & (j-1));
            int l = i | j;
            bool asc = (((base + i) & k) == 0);
            u64 A = s[i], B = s[l];
            bool sw = asc ? (A > B) : (A < B);
            if (sw) { s[i] = B; s[l] = A; }
        }
        __syncthreads();
    }
    for (int t = threadIdx.x; t < 8192; t += 1024) keys[base + t] = s[t];
}

__global__ __launch_bounds__(256) void k_sortG(u64* __restrict__ keys, int k, int j) {
    int t = blockIdx.x * 256 + threadIdx.x;    // 16384 pairs
    int i = ((t & ~(j-1)) << 1) | (t & (j-1));
    int l = i | j;
    bool asc = ((i & k) == 0);
    u64 A = keys[i], B = keys[l];
    bool sw = asc ? (A > B) : (A < B);
    if (sw) { keys[i] = B; keys[l] = A; }
}

// ---------------------------------------------------------------- gather top-12000
__global__ __launch_bounds__(256) void k_gather(const u64* __restrict__ keys,
                                                const double* __restrict__ roi64,
                                                double* __restrict__ sbox,
                                                double* __restrict__ sarea,
                                                u64* __restrict__ suppinit) {
    int p = blockIdx.x * 256 + threadIdx.x;    // grid 48 -> 12288
    bool sup = true;
    if (p < PRE) {
        int idx = (int)(keys[p] & 0xFFFFull);
        double b0 = roi64[4*idx+0], b1 = roi64[4*idx+1];
        double b2 = roi64[4*idx+2], b3 = roi64[4*idx+3];
        sbox[4*p+0] = b0; sbox[4*p+1] = b1; sbox[4*p+2] = b2; sbox[4*p+3] = b3;
        sarea[p] = (b3 - b1 + 1.0) * (b2 - b0 + 1.0);
        sup = !((b2 - b0 >= 16.0) && (b3 - b1 >= 16.0));
    } else {
        sbox[4*p+0] = 0.0; sbox[4*p+1] = 0.0; sbox[4*p+2] = 0.0; sbox[4*p+3] = 0.0;
        sarea[p] = 1.0;
    }
    u64 ball = __ballot(sup);
    if ((threadIdx.x & 63) == 0) suppinit[p >> 6] = ball;
}

// ---------------------------------------------------------------- suppression bit matrix
__global__ __launch_bounds__(256) void k_mask(const double* __restrict__ sbox,
                                              const double* __restrict__ sarea,
                                              u64* __restrict__ mask) {
    const int jt = blockIdx.x, it = blockIdx.y;     // (12, 188)
    const int ib = it * 64, jb0 = jt * 1024;
    if (jb0 + 1023 <= ib) {                         // whole tile has j <= i -> zeros
        for (int t = threadIdx.x; t < 1024; t += 256) {
            int ti = t >> 4, w = t & 15;
            int i = ib + ti;
            if (i < PRE) mask[(size_t)i * ROWW + jt*16 + w] = 0ull;
        }
        return;
    }
    __shared__ double jbx[4096];
    __shared__ double jar[1024];
    for (int t = threadIdx.x; t < 4096; t += 256) jbx[t] = sbox[(size_t)jb0*4 + t];
    for (int t = threadIdx.x; t < 1024; t += 256) jar[t] = sarea[jb0 + t];
    __syncthreads();
    int ti = threadIdx.x >> 2;
    int i = ib + ti;
    if (i >= PRE) return;
    double iy1 = sbox[4*i+0], ix1 = sbox[4*i+1], iy2 = sbox[4*i+2], ix2 = sbox[4*i+3];
    double iar = sarea[i];
    for (int w = (threadIdx.x & 3); w < 16; w += 4) {
        u64 bits = 0ull;
        int q0 = w * 64;
        for (int l = 0; l < 64; ++l) {
            int q = q0 + l;
            double jy1 = jbx[4*q+0], jx1 = jbx[4*q+1], jy2 = jbx[4*q+2], jx2 = jbx[4*q+3];
            double yy1 = fmax(iy1, jy1), xx1 = fmax(ix1, jx1);
            double yy2 = fmin(iy2, jy2), xx2 = fmin(ix2, jx2);
            double iw = fmax(xx2 - xx1 + 1.0, 0.0);
            double ih = fmax(yy2 - yy1 + 1.0, 0.0);
            double inter = iw * ih;
            bool s = ((jb0 + q) > i) && (inter > 0.7 * (iar + jar[q] - inter));
            bits |= ((u64)s) << l;
        }
        mask[(size_t)i * ROWW + jt*16 + w] = bits;
    }
}

// ---------------------------------------------------------------- helpers for k_scan
__device__ inline u64 rdl64(u64 v, int l) {
    u32 lo = (u32)__builtin_amdgcn_readlane((int)(u32)v, l);
    u32 hi = (u32)__builtin_amdgcn_readlane((int)(u32)(v >> 32), l);
    return ((u64)hi << 32) | (u64)lo;
}
#define RFL64(lo, hi) ( ((u64)(u32)__builtin_amdgcn_readfirstlane((int)(hi)) << 32) \
                      | (u64)(u32)__builtin_amdgcn_readfirstlane((int)(lo)) )

// ---------------------------------------------------------------- NMS scan v4:
// 512 threads. Phase A (concurrent): wave0 scans chunk c; waves 1-3 prefetch
// diag(c+1); waves 4-7 compute supp-partial(c+1) from kept rows known at
// chunk start (the formerly-serialized JIT pass, now in the scan's shadow).
// Phase B: OR only the newly-kept rows (~kc) into supp(c+1) + re-init the
// alternate supp buffer for chunk c+2.
__global__ __launch_bounds__(512) void k_scan(const u64* __restrict__ mask,
                                              const u64* __restrict__ suppinit,
                                              const double* __restrict__ sbox,
                                              float* __restrict__ rois) {
    __shared__ u64 dbuf[2][4608];     // [buf][row*9 + w], 512 rows x 8(+1 pad) words
    __shared__ u32 keptLDS[POST];     // global sorted indices of kept boxes
    __shared__ u32 supp8[2][16];      // chunk supp words as u32 pairs
    __shared__ int rankS, doneS;
    const int tid = threadIdx.x;
    const u32* suppinit32 = (const u32*)suppinit;

    if (tid < 16)                 supp8[0][tid]      = suppinit32[tid];       // chunk 0
    else if (tid < 32)            supp8[1][tid - 16] = suppinit32[tid];       // chunk 1
    if (tid == 0) { rankS = 0; doneS = 0; }
    for (int q = tid; q < 4096; q += 512) {
        int r = q >> 3, w = q & 7;
        dbuf[0][r*9 + w] = (r < PRE) ? mask[(size_t)r * ROWW + w] : 0ull;
    }
    __syncthreads();

    int rank0 = 0;                    // rank at start of current chunk (uniform)
    for (int c = 0; c < 24; ++c) {
        const int nc = c + 1;
        const int cb = c & 1, nb = nc & 1;
        if (tid < 64) {
            // ---------- wave 0: scan chunk c ----------
            const int lane = tid;
            u64 i0 = RFL64(supp8[cb][0],  supp8[cb][1]);
            u64 i1 = RFL64(supp8[cb][2],  supp8[cb][3]);
            u64 i2 = RFL64(supp8[cb][4],  supp8[cb][5]);
            u64 i3 = RFL64(supp8[cb][6],  supp8[cb][7]);
            u64 i4 = RFL64(supp8[cb][8],  supp8[cb][9]);
            u64 i5 = RFL64(supp8[cb][10], supp8[cb][11]);
            u64 i6 = RFL64(supp8[cb][12], supp8[cb][13]);
            u64 i7 = RFL64(supp8[cb][14], supp8[cb][15]);
            u64 a0=0,a1=0,a2=0,a3=0,a4=0,a5=0,a6=0,a7=0;
            int rk = __builtin_amdgcn_readfirstlane(rankS);
            bool dn = false;
#define GROUP(G)                                                                \
            if (!dn) {                                                          \
                u64 z = ~(i##G | a##G);                                         \
                if (z) {                                                        \
                    u64 r0=0,r1=0,r2=0,r3=0,r4=0,r5=0,r6=0,r7=0;                \
                    if ((z >> lane) & 1ull) {                                   \
                        const u64* rowp = &dbuf[cb][(G*64 + lane)*9];           \
                        r0=rowp[0]; r1=rowp[1]; r2=rowp[2]; r3=rowp[3];         \
                        r4=rowp[4]; r5=rowp[5]; r6=rowp[6]; r7=rowp[7];         \
                    }                                                           \
                    u64 keptm = 0;                                              \
                    while (z) {                                                 \
                        int bpos = (int)__builtin_ctzll(z);                     \
                        u64 q0=rdl64(r0,bpos), q1=rdl64(r1,bpos);               \
                        u64 q2=rdl64(r2,bpos), q3=rdl64(r3,bpos);               \
                        u64 q4=rdl64(r4,bpos), q5=rdl64(r5,bpos);               \
                        u64 q6=rdl64(r6,bpos), q7=rdl64(r7,bpos);               \
                        keptm |= (1ull << bpos);                                \
                        z &= ~(1ull << bpos) & ~q##G;                           \
                        a0|=q0; a1|=q1; a2|=q2; a3|=q3;                         \
                        a4|=q4; a5|=q5; a6|=q6; a7|=q7;                         \
                    }                                                           \
                    int pc = __builtin_popcountll(keptm);                       \
                    int navail = POST - rk;                                     \
                    int mylot = __builtin_amdgcn_mbcnt_hi((u32)(keptm >> 32),   \
                                 __builtin_amdgcn_mbcnt_lo((u32)keptm, 0));     \
                    if (((keptm >> lane) & 1) && mylot < navail)                \
                        keptLDS[rk + mylot] = (u32)(c*512 + G*64 + lane);       \
                    if (pc >= navail) { rk = POST; dn = true; }                 \
                    else rk += pc;                                              \
                }                                                               \
            }
            GROUP(0) GROUP(1) GROUP(2) GROUP(3)
            GROUP(4) GROUP(5) GROUP(6) GROUP(7)
#undef GROUP
            if (lane == 0) { rankS = rk; if (dn) doneS = 1; }
        } else if (tid < 256) {
            // ---------- waves 1..3: prefetch diag block of chunk nc ----------
            if (nc < 24) {
                for (int q = tid - 64; q < 4096; q += 192) {
                    int r = q >> 3, w = q & 7;
                    int i = nc*512 + r;
                    dbuf[nb][r*9 + w] = (i < PRE) ? mask[(size_t)i * ROWW + nc*8 + w] : 0ull;
                }
            }
        } else {
            // ---------- waves 4..7: supp-partial(nc) from kept[0, rank0) ----------
            if (nc < 24 && rank0 > 0) {
                u64 acc[8] = {0,0,0,0,0,0,0,0};
                for (int k = tid - 256; k < rank0; k += 256) {
                    const u64* rp = mask + (size_t)keptLDS[k] * ROWW + nc*8;
                    #pragma unroll
                    for (int w = 0; w < 8; ++w) acc[w] |= rp[w];
                }
                #pragma unroll
                for (int w = 0; w < 8; ++w) {
                    u64 v = acc[w];
                    #pragma unroll
                    for (int s = 1; s < 64; s <<= 1)
                        v |= (u64)__shfl_xor((unsigned long long)v, s, 64);
                    if ((tid & 63) == 0) {
                        if ((u32)v)         atomicOr(&supp8[nb][2*w],   (u32)v);
                        if ((u32)(v >> 32)) atomicOr(&supp8[nb][2*w+1], (u32)(v >> 32));
                    }
                }
            }
        }
        __syncthreads();                           // barrier 1
        if (doneS) break;
        if (nc >= 24) break;
        const int rk1 = rankS;
        // ---------- phase B: merge new kept [rank0, rk1) + init supp(c+2) ----------
        {
            int w = tid & 7;
            u64 acc = 0;
            for (int k = rank0 + (tid >> 3); k < rk1; k += 64)
                acc |= mask[(size_t)keptLDS[k] * ROWW + nc*8 + w];
            if ((u32)acc)         atomicOr(&supp8[nb][2*w],   (u32)acc);
            if ((u32)(acc >> 32)) atomicOr(&supp8[nb][2*w+1], (u32)(acc >> 32));
            if (tid < 16) supp8[cb][tid] = (c + 2 < 24) ? suppinit32[(c+2)*16 + tid] : 0u;
        }
        rank0 = rk1;
        __syncthreads();                           // barrier 2
    }
    __syncthreads();
    const int R = rankS;
    for (int r = tid; r < POST; r += 512) {
        if (r < R) {
            int p = (int)keptLDS[r];
            rois[4*r+0] = (float)sbox[4*p+0];
            rois[4*r+1] = (float)sbox[4*p+1];
            rois[4*r+2] = (float)sbox[4*p+2];
            rois[4*r+3] = (float)sbox[4*p+3];
        } // else stays zero (memset)
    }
}

// ---------------------------------------------------------------- launcher
extern "C" void kernel_launch(void* const* d_in, const int* in_sizes, int n_in,
                              void* d_out, int out_size, void* d_ws, size_t ws_size,
                              hipStream_t stream) {
    const float* x    = (const float*)d_in[0];
    const float* w1   = (const float*)d_in[1];
    const float* b1   = (const float*)d_in[2];
    const float* regw = (const float*)d_in[3];
    const float* regb = (const float*)d_in[4];
    const float* clsw = (const float*)d_in[5];
    const float* clsb = (const float*)d_in[6];
    float* out = (float*)d_out;

    char* ws = (char*)d_ws;
    double* w64    = (double*)(ws + OFF_W64);
    double* h64    = (double*)(ws + OFF_H64);
    double* reg64  = (double*)(ws + OFF_REG64);
    double* sc64   = (double*)(ws + OFF_SC64);
    double* roi64  = (double*)(ws + OFF_ROI64);
    u64*    keys   = (u64*)   (ws + OFF_KEYS);
    double* sbox   = (double*)(ws + OFF_SBOX);
    double* sarea  = (double*)(ws + OFF_SAREA);
    u64*    supp0  = (u64*)   (ws + OFF_SUPP);
    u64*    maskp  = (u64*)   (ws + OFF_MASK);
    float*  xpad   = (float*) (ws + OFF_XPAD);   // aliases mask region (used before k_mask)
    double* h64b   = (double*)(ws + OFF_H64B);   // aliases mask region (used before k_mask)

    hipMemsetAsync(d_out, 0, 8000 * sizeof(float), stream);  // rois zero-padding

    k_prepx<<<2916, 256, 0, stream>>>(x, xpad);
    k_prepw<<<2304, 256, 0, stream>>>(w1, w64);
    k_conv3<<<dim3(11, 64, 2), 256, 0, stream>>>(xpad, w64, b1, h64, h64b);
    k_conv1<<<dim3(43, 6), 64, 0, stream>>>(h64, h64b, regw, regb, clsw, clsb, out, reg64, sc64);
    k_decode<<<128, 256, 0, stream>>>(reg64, sc64, roi64, keys);

    k_sortA<<<4, 1024, 0, stream>>>(keys);
    k_sortG<<<64, 256, 0, stream>>>(keys, 16384, 8192);
    k_sortB<<<4, 1024, 0, stream>>>(keys, 16384);
    k_sortG<<<64, 256, 0, stream>>>(keys, 32768, 16384);
    k_sortG<<<64, 256, 0, stream>>>(keys, 32768, 8192);
    k_sortB<<<4, 1024, 0, stream>>>(keys, 32768);

    k_gather<<<48, 256, 0, stream>>>(keys, roi64, sbox, sarea, supp0);
    k_mask<<<dim3(12, 188), 256, 0, stream>>>(sbox, sarea, maskp);
    k_scan<<<1, 512, 0, stream>>>(maskp, supp0, sbox, out + ROIS_OFF);
}